// Round 10
// baseline (496.348 us; speedup 1.0000x reference)
//
#include <hip/hip_runtime.h>
#include <hip/hip_bf16.h>
#include <math.h>

#define N_NODES   50000
#define N_EDGES   800000
#define N_GRAPHS  64
#define IN_CH     128
#define GLOBAL_DIM 256
#define HIDDEN    64
#define HEADS     4
#define N_CLASSES 10
#define QKV_COLS  832   // 256 q | 256 k | 256 v | 64 skip

typedef unsigned short ushort_t;
typedef unsigned int uint_t;
typedef unsigned char uchar_t;
typedef __attribute__((ext_vector_type(8))) short short8;
typedef __attribute__((ext_vector_type(4))) float floatx4;
typedef __attribute__((ext_vector_type(2))) float floatx2;

// ---------------------------------------------------------------------------
// helpers
// ---------------------------------------------------------------------------
__device__ __forceinline__ ushort_t bf16rne(float f) {
    uint_t b = __float_as_uint(f);
    b += 0x7fffu + ((b >> 16) & 1u);
    return (ushort_t)(b >> 16);
}
__device__ __forceinline__ float4 bf4_unpack(uint_t lo, uint_t hi) {
    float4 f;
    f.x = __uint_as_float(lo << 16);
    f.y = __uint_as_float(lo & 0xffff0000u);
    f.z = __uint_as_float(hi << 16);
    f.w = __uint_as_float(hi & 0xffff0000u);
    return f;
}
__device__ __forceinline__ uchar_t fp8e4m3(float f) {
    int v = __builtin_amdgcn_cvt_pk_fp8_f32(f, 0.f, 0, false);
    return (uchar_t)(v & 0xff);
}
__device__ __forceinline__ short8 pack_bf8(float4 a, float4 b) {
    union { short8 s; ushort_t u[8]; } r;
    r.u[0] = bf16rne(a.x); r.u[1] = bf16rne(a.y);
    r.u[2] = bf16rne(a.z); r.u[3] = bf16rne(a.w);
    r.u[4] = bf16rne(b.x); r.u[5] = bf16rne(b.y);
    r.u[6] = bf16rne(b.z); r.u[7] = bf16rne(b.w);
    return r.s;
}

// ---------------------------------------------------------------------------
// PREP: concat both layers' weights  ||  count_deg   (no x-cast anymore)
// ---------------------------------------------------------------------------
#define PREP_CONC_B  624
#define PREP_CNT_B   1024
#define PREP_BLOCKS  (PREP_CONC_B + PREP_CNT_B)

__global__ __launch_bounds__(256) void prep2(
        const float* __restrict__ W1q, const float* __restrict__ W1k,
        const float* __restrict__ W1v, const float* __restrict__ W1s,
        const float* __restrict__ b1q, const float* __restrict__ b1k,
        const float* __restrict__ b1v, const float* __restrict__ b1s,
        const float* __restrict__ W2q, const float* __restrict__ W2k,
        const float* __restrict__ W2v, const float* __restrict__ W2s,
        const float* __restrict__ b2q, const float* __restrict__ b2k,
        const float* __restrict__ b2v, const float* __restrict__ b2s,
        ushort_t* __restrict__ Wt1, ushort_t* __restrict__ Wt2,
        float* __restrict__ bcat1, float* __restrict__ bcat2,
        const int* __restrict__ dst, int* __restrict__ deg) {
    int b = blockIdx.x, t = threadIdx.x;
    if (b < PREP_CONC_B) {
        int idx = b * 256 + t;
        const int T1 = IN_CH * QKV_COLS;
        const int T2 = HIDDEN * QKV_COLS;
        if (idx < T1) {
            int c = idx / IN_CH, k = idx % IN_CH;
            float v;
            if (c < 256)      v = W1q[k * 256 + c];
            else if (c < 512) v = W1k[k * 256 + (c - 256)];
            else if (c < 768) v = W1v[k * 256 + (c - 512)];
            else              v = W1s[k * 64  + (c - 768)];
            Wt1[idx] = bf16rne(v);
        } else if (idx < T1 + T2) {
            int i2 = idx - T1;
            int c = i2 / HIDDEN, k = i2 % HIDDEN;
            float v;
            if (c < 256)      v = W2q[k * 256 + c];
            else if (c < 512) v = W2k[k * 256 + (c - 256)];
            else if (c < 768) v = W2v[k * 256 + (c - 512)];
            else              v = W2s[k * 64  + (c - 768)];
            Wt2[i2] = bf16rne(v);
        }
        if (idx < QKV_COLS) {
            float bb, b2;
            if (idx < 256)      { bb = b1q[idx];       b2 = b2q[idx]; }
            else if (idx < 512) { bb = b1k[idx - 256]; b2 = b2k[idx - 256]; }
            else if (idx < 768) { bb = b1v[idx - 512]; b2 = b2v[idx - 512]; }
            else                { bb = b1s[idx - 768]; b2 = b2s[idx - 768]; }
            bcat1[idx] = bb;
            bcat2[idx] = b2;
        }
    } else {
        int idx = (b - PREP_CONC_B) * 256 + t;
        for (int e = idx; e < N_EDGES; e += PREP_CNT_B * 256)
            atomicAdd(&deg[dst[e]], 1);
    }
}

// ---------------------------------------------------------------------------
// scans
// ---------------------------------------------------------------------------
__global__ void scan1(const int* __restrict__ deg, int* __restrict__ incl,
                      int* __restrict__ bsums, int n) {
    __shared__ int sh[1024];
    int t = threadIdx.x;
    int gid = blockIdx.x * 1024 + t;
    int v = (gid < n) ? deg[gid] : 0;
    sh[t] = v;
    __syncthreads();
    for (int off = 1; off < 1024; off <<= 1) {
        int tmp = (t >= off) ? sh[t - off] : 0;
        __syncthreads();
        sh[t] += tmp;
        __syncthreads();
    }
    if (gid < n) incl[gid] = sh[t];
    if (t == 1023) bsums[blockIdx.x] = sh[1023];
}

__global__ void scan3f(const int* __restrict__ deg, const int* __restrict__ incl,
                       const int* __restrict__ bsums, int* __restrict__ rowptr,
                       int* __restrict__ cur, int n) {
    __shared__ int sb;
    int t = threadIdx.x;
    int b = (int)(blockIdx.x >> 2);
    if (t < 64) {
        int v = (t < b) ? bsums[t] : 0;
#pragma unroll
        for (int off = 1; off < 64; off <<= 1) v += __shfl_xor(v, off);
        if (t == 0) sb = v;
    }
    __syncthreads();
    int gid = blockIdx.x * 256 + t;
    if (gid < n) {
        int in = incl[gid] + sb;
        int ex = in - deg[gid];
        rowptr[gid] = ex;
        cur[gid] = ex;
        if (gid == n - 1) rowptr[n] = in;
    }
}

__global__ void fill_col(const int* __restrict__ src, const int* __restrict__ dst,
                         int* __restrict__ cur, int* __restrict__ col) {
    int e = blockIdx.x * 256 + threadIdx.x;
    if (e < N_EDGES) {
        int d = dst[e];
        int pos = atomicAdd(&cur[d], 1);
        col[pos] = src[e];
    }
}

// ---------------------------------------------------------------------------
// GEMM v8: LDS-free mainloop (A + L2-resident Wt direct from global);
// LDS only for the coalescing epilogue tile. A is fp32 (conv1, cast in-reg)
// or bf16 (conv2). XCD-swizzled 1D grid.
// Outputs: ct 0-3 q fp8 | ct 4-7 k fp8 | ct 8-11 v fp8 | ct 12 skip bf16.
// ---------------------------------------------------------------------------
template <int K, bool A_FP32>
__global__ __launch_bounds__(256) void gemm_v8(const void* __restrict__ Av,
                                               const ushort_t* __restrict__ Wt,
                                               const float* __restrict__ bias,
                                               uchar_t* __restrict__ qb8,
                                               uchar_t* __restrict__ kvb,
                                               ushort_t* __restrict__ skipb,
                                               int N, int RB) {
    __shared__ uchar_t smem[10240] __attribute__((aligned(16)));
    const int t = threadIdx.x;
    const int idx0 = (int)blockIdx.x;
    const int xcd = idx0 & 7;
    const int j = idx0 >> 3;
    const int ct = j % 13;
    const int strip = (j / 13) * 8 + xcd;
    if (strip >= RB) return;
    const int base_r = strip * 128;
    const int base_c = ct * 64;

    const int wave = t >> 6, lane = t & 63;
    const int quad = lane >> 4, m16 = lane & 15;

    // A fragments direct from global
    int arow0 = base_r + wave * 32 + m16;
    int arow1 = arow0 + 16;
    int cr0 = arow0 < N ? arow0 : N - 1;
    int cr1 = arow1 < N ? arow1 : N - 1;
    short8 a0[K / 32], a1[K / 32];
    if (A_FP32) {
        const float* A = (const float*)Av;
        const float* Ar0 = A + (size_t)cr0 * K + quad * 8;
        const float* Ar1 = A + (size_t)cr1 * K + quad * 8;
#pragma unroll
        for (int kc = 0; kc < K / 32; ++kc) {
            float4 f0 = *(const float4*)(Ar0 + kc * 32);
            float4 f1 = *(const float4*)(Ar0 + kc * 32 + 4);
            a0[kc] = pack_bf8(f0, f1);
            float4 g0 = *(const float4*)(Ar1 + kc * 32);
            float4 g1 = *(const float4*)(Ar1 + kc * 32 + 4);
            a1[kc] = pack_bf8(g0, g1);
        }
    } else {
        const ushort_t* A = (const ushort_t*)Av;
        const ushort_t* Ar0 = A + (size_t)cr0 * K + quad * 8;
        const ushort_t* Ar1 = A + (size_t)cr1 * K + quad * 8;
#pragma unroll
        for (int kc = 0; kc < K / 32; ++kc) {
            a0[kc] = *(const short8*)(Ar0 + kc * 32);
            a1[kc] = *(const short8*)(Ar1 + kc * 32);
        }
    }

    // B fragments direct from global (Wt row = output col, L2-resident)
    const ushort_t* Wb = Wt + (size_t)(base_c + m16) * K + quad * 8;

    floatx4 acc[2][4];
#pragma unroll
    for (int rt = 0; rt < 2; ++rt)
#pragma unroll
        for (int c2 = 0; c2 < 4; ++c2) acc[rt][c2] = (floatx4){0.f, 0.f, 0.f, 0.f};
#pragma unroll
    for (int kc = 0; kc < K / 32; ++kc) {
#pragma unroll
        for (int c2 = 0; c2 < 4; ++c2) {
            short8 b = *(const short8*)(Wb + (size_t)(c2 * 16) * K + kc * 32);
            acc[0][c2] = __builtin_amdgcn_mfma_f32_16x16x32_bf16(a0[kc], b, acc[0][c2], 0, 0, 0);
            acc[1][c2] = __builtin_amdgcn_mfma_f32_16x16x32_bf16(a1[kc], b, acc[1][c2], 0, 0, 0);
        }
    }

    float bb[4];
#pragma unroll
    for (int c2 = 0; c2 < 4; ++c2) bb[c2] = bias[base_c + c2 * 16 + m16];
#pragma unroll
    for (int rt = 0; rt < 2; ++rt)
#pragma unroll
        for (int c2 = 0; c2 < 4; ++c2)
#pragma unroll
            for (int r = 0; r < 4; ++r) acc[rt][c2][r] += bb[c2];

    // epilogue: lane elem (rt,c2,r) -> row_l = wave*32+rt*16+quad*4+r, col_l = c2*16+m16
    if (ct < 12) {
        uchar_t* ep = smem;    // fp8 tile [128][stride 80]
#pragma unroll
        for (int c2 = 0; c2 < 4; ++c2) {
            int col_l = c2 * 16 + m16;
#pragma unroll
            for (int rt = 0; rt < 2; ++rt)
#pragma unroll
                for (int r = 0; r < 4; ++r)
                    ep[(wave * 32 + rt * 16 + quad * 4 + r) * 80 + col_l] =
                        fp8e4m3(acc[rt][c2][r]);
        }
        __syncthreads();
        uchar_t* dstbase;
        size_t rstride;
        int off;
        if (ct < 4)      { dstbase = qb8; rstride = 256; off = base_c; }
        else if (ct < 8) { dstbase = kvb; rstride = 512; off = base_c - 256; }
        else             { dstbase = kvb; rstride = 512; off = 256 + (base_c - 512); }
#pragma unroll
        for (int i = 0; i < 2; ++i) {
            int ii = t + i * 256;
            int row = ii >> 2, ch = ii & 3;
            int gr = base_r + row;
            if (gr < N)
                *(uint4*)(dstbase + (size_t)gr * rstride + off + ch * 16) =
                    *(const uint4*)(ep + row * 80 + ch * 16);
        }
    } else {
        // skip: bf16, two 64-row passes (LDS stride 68 ushorts, 8704 B)
        ushort_t* ep = (ushort_t*)smem;
#pragma unroll
        for (int p = 0; p < 2; ++p) {
            if ((wave >> 1) == p) {
#pragma unroll
                for (int c2 = 0; c2 < 4; ++c2) {
                    int col_l = c2 * 16 + m16;
#pragma unroll
                    for (int rt = 0; rt < 2; ++rt)
#pragma unroll
                        for (int r = 0; r < 4; ++r)
                            ep[((wave & 1) * 32 + rt * 16 + quad * 4 + r) * 68 + col_l] =
                                bf16rne(acc[rt][c2][r]);
                }
            }
            __syncthreads();
#pragma unroll
            for (int i = 0; i < 2; ++i) {
                int ii = t + i * 256;
                int row = ii >> 3, ch = ii & 7;
                int gr = base_r + p * 64 + row;
                if (gr < N)
                    *(uint4*)(skipb + (size_t)gr * 64 + ch * 8) =
                        *(const uint4*)(ep + row * 68 + ch * 8);
            }
            __syncthreads();
        }
    }
}

// ---------------------------------------------------------------------------
// attn v7: packed-fp32 math; q pre-scaled by 1/8; head-mean 0.25 folded in 1/z.
// kvb: node*512 + [0:256)=k fp8, [256:512)=v fp8. sl=lane&31 owns 8 dims.
// ---------------------------------------------------------------------------
__device__ __forceinline__ void edge_step3(uint2 k8, uint2 v8, const floatx2* qp,
                                           float& z, floatx2* acp) {
    floatx2 dp = qp[0] * __builtin_amdgcn_cvt_pk_f32_fp8(k8.x, false);
    dp += qp[1] * __builtin_amdgcn_cvt_pk_f32_fp8(k8.x, true);
    dp += qp[2] * __builtin_amdgcn_cvt_pk_f32_fp8(k8.y, false);
    dp += qp[3] * __builtin_amdgcn_cvt_pk_f32_fp8(k8.y, true);
    float d = dp[0] + dp[1];
    d += __shfl_xor(d, 1);
    d += __shfl_xor(d, 2);
    d += __shfl_xor(d, 4);
    float p = __expf(d);           // q already scaled by 1/8
    z += p;
    floatx2 pp = {p, p};
    acp[0] += pp * __builtin_amdgcn_cvt_pk_f32_fp8(v8.x, false);
    acp[1] += pp * __builtin_amdgcn_cvt_pk_f32_fp8(v8.x, true);
    acp[2] += pp * __builtin_amdgcn_cvt_pk_f32_fp8(v8.y, false);
    acp[3] += pp * __builtin_amdgcn_cvt_pk_f32_fp8(v8.y, true);
}

template <bool OUT_BF16>
__global__ __launch_bounds__(256) void attn_agg7(const uchar_t* __restrict__ qb8,
                                                 const uchar_t* __restrict__ kvb,
                                                 const ushort_t* __restrict__ skipb,
                                                 const int* __restrict__ rowptr,
                                                 const int* __restrict__ col,
                                                 void* __restrict__ hout) {
    int node = blockIdx.x * 4 + threadIdx.y;
    if (node >= N_NODES) return;
    int lane = threadIdx.x;
    int half = lane >> 5, sl = lane & 31;
    uint2 qd = *(const uint2*)(qb8 + (size_t)node * 256 + sl * 8);
    const floatx2 s8 = {0.125f, 0.125f};
    floatx2 qp[4];
    qp[0] = s8 * __builtin_amdgcn_cvt_pk_f32_fp8(qd.x, false);
    qp[1] = s8 * __builtin_amdgcn_cvt_pk_f32_fp8(qd.x, true);
    qp[2] = s8 * __builtin_amdgcn_cvt_pk_f32_fp8(qd.y, false);
    qp[3] = s8 * __builtin_amdgcn_cvt_pk_f32_fp8(qd.y, true);
    floatx2 acp[4];
    acp[0] = (floatx2){0.f, 0.f}; acp[1] = (floatx2){0.f, 0.f};
    acp[2] = (floatx2){0.f, 0.f}; acp[3] = (floatx2){0.f, 0.f};
    float z = 0.f;
    int beg = rowptr[node], end = rowptr[node + 1];
    int e = beg + half;
    const size_t loff = (size_t)sl * 8;
    for (; e + 6 < end; e += 8) {
        const uchar_t* p0 = kvb + (size_t)col[e]     * 512 + loff;
        const uchar_t* p1 = kvb + (size_t)col[e + 2] * 512 + loff;
        const uchar_t* p2 = kvb + (size_t)col[e + 4] * 512 + loff;
        const uchar_t* p3 = kvb + (size_t)col[e + 6] * 512 + loff;
        uint2 k0 = *(const uint2*)p0, v0 = *(const uint2*)(p0 + 256);
        uint2 k1 = *(const uint2*)p1, v1 = *(const uint2*)(p1 + 256);
        uint2 k2 = *(const uint2*)p2, v2 = *(const uint2*)(p2 + 256);
        uint2 k3 = *(const uint2*)p3, v3 = *(const uint2*)(p3 + 256);
        edge_step3(k0, v0, qp, z, acp);
        edge_step3(k1, v1, qp, z, acp);
        edge_step3(k2, v2, qp, z, acp);
        edge_step3(k3, v3, qp, z, acp);
    }
    for (; e < end; e += 2) {
        const uchar_t* p0 = kvb + (size_t)col[e] * 512 + loff;
        uint2 k0 = *(const uint2*)p0, v0 = *(const uint2*)(p0 + 256);
        edge_step3(k0, v0, qp, z, acp);
    }
    z += __shfl_xor(z, 32);
    float ac[8] = {acp[0][0], acp[0][1], acp[1][0], acp[1][1],
                   acp[2][0], acp[2][1], acp[3][0], acp[3][1]};
#pragma unroll
    for (int i = 0; i < 8; ++i) ac[i] += __shfl_xor(ac[i], 32);
    float inv = (z > 0.f) ? (0.25f / z) : 0.f;   // head-mean folded in
#pragma unroll
    for (int i = 0; i < 8; ++i) ac[i] *= inv;
#pragma unroll
    for (int i = 0; i < 8; ++i) {
        ac[i] += __shfl_xor(ac[i], 8);
        ac[i] += __shfl_xor(ac[i], 16);
    }
    if (lane < 8) {
        uint4 su = *(const uint4*)(skipb + (size_t)node * 64 + lane * 8);
        float4 s0 = bf4_unpack(su.x, su.y);
        float4 s1 = bf4_unpack(su.z, su.w);
        float o0 = fmaxf(ac[0] + s0.x, 0.f);
        float o1 = fmaxf(ac[1] + s0.y, 0.f);
        float o2 = fmaxf(ac[2] + s0.z, 0.f);
        float o3 = fmaxf(ac[3] + s0.w, 0.f);
        float o4 = fmaxf(ac[4] + s1.x, 0.f);
        float o5 = fmaxf(ac[5] + s1.y, 0.f);
        float o6 = fmaxf(ac[6] + s1.z, 0.f);
        float o7 = fmaxf(ac[7] + s1.w, 0.f);
        if (OUT_BF16) {
            uint4 u;
            u.x = (uint_t)bf16rne(o0) | ((uint_t)bf16rne(o1) << 16);
            u.y = (uint_t)bf16rne(o2) | ((uint_t)bf16rne(o3) << 16);
            u.z = (uint_t)bf16rne(o4) | ((uint_t)bf16rne(o5) << 16);
            u.w = (uint_t)bf16rne(o6) | ((uint_t)bf16rne(o7) << 16);
            *(uint4*)((ushort_t*)hout + (size_t)node * HIDDEN + lane * 8) = u;
        } else {
            float* op = (float*)hout + (size_t)node * HIDDEN + lane * 8;
            *(float4*)(op)     = make_float4(o0, o1, o2, o3);
            *(float4*)(op + 4) = make_float4(o4, o5, o6, o7);
        }
    }
}

// ---------------------------------------------------------------------------
// pool + head fused: one 256-thread block per graph
// ---------------------------------------------------------------------------
__global__ __launch_bounds__(256) void pool_head(const float* __restrict__ h,
                                                 const int* __restrict__ batch,
                                                 const float* __restrict__ gf,
                                                 const float* __restrict__ gW1, const float* __restrict__ gb1,
                                                 const float* __restrict__ gW2, const float* __restrict__ gb2,
                                                 const float* __restrict__ hW1, const float* __restrict__ hb1,
                                                 const float* __restrict__ hW2, const float* __restrict__ hb2,
                                                 float* __restrict__ out) {
    int g = blockIdx.x;
    int lo = 0, hi = N_NODES;
    while (lo < hi) { int mid = (lo + hi) >> 1; if (batch[mid] < g) lo = mid + 1; else hi = mid; }
    int start = lo;
    hi = N_NODES;
    while (lo < hi) { int mid = (lo + hi) >> 1; if (batch[mid] < g + 1) lo = mid + 1; else hi = mid; }
    int end = lo;
    int t = threadIdx.x;
    int d = t & 63, chunk = t >> 6;
    float acc = 0.f;
    for (int n = start + chunk; n < end; n += 4) acc += h[(size_t)n * HIDDEN + d];
    __shared__ float sh[256];
    __shared__ float gfs[GLOBAL_DIM];
    __shared__ float fused[2 * HIDDEN];
    __shared__ float g1[HIDDEN];
    __shared__ float h1s[HIDDEN];
    sh[t] = acc;
    gfs[t] = gf[(size_t)g * GLOBAL_DIM + t];
    __syncthreads();
    if (chunk == 0) {
        float cnt = fmaxf((float)(end - start), 1.0f);
        fused[d] = (sh[d] + sh[64 + d] + sh[128 + d] + sh[192 + d]) / cnt;
        float a = gb1[d];
        for (int k = 0; k < GLOBAL_DIM; ++k) a = fmaf(gfs[k], gW1[k * HIDDEN + d], a);
        g1[d] = fmaxf(a, 0.f);
    }
    __syncthreads();
    if (chunk == 0) {
        float a = gb2[d];
        for (int k = 0; k < HIDDEN; ++k) a = fmaf(g1[k], gW2[k * HIDDEN + d], a);
        fused[HIDDEN + d] = fmaxf(a, 0.f);
    }
    __syncthreads();
    if (chunk == 0) {
        float a = hb1[d];
        for (int k = 0; k < 2 * HIDDEN; ++k) a = fmaf(fused[k], hW1[k * HIDDEN + d], a);
        h1s[d] = fmaxf(a, 0.f);
    }
    __syncthreads();
    if (t < N_CLASSES) {
        float o = hb2[t];
        for (int k = 0; k < HIDDEN; ++k) o = fmaf(h1s[k], hW2[k * N_CLASSES + t], o);
        out[(size_t)g * N_CLASSES + t] = o;
    }
}

// ---------------------------------------------------------------------------
extern "C" void kernel_launch(void* const* d_in, const int* in_sizes, int n_in,
                              void* d_out, int out_size, void* d_ws, size_t ws_size,
                              hipStream_t stream) {
    const float* x        = (const float*)d_in[0];
    const int*   eidx     = (const int*)d_in[1];
    const int*   batch    = (const int*)d_in[2];
    const float* gfeats   = (const float*)d_in[3];
    const float* c1_Wq = (const float*)d_in[4];  const float* c1_bq = (const float*)d_in[5];
    const float* c1_Wk = (const float*)d_in[6];  const float* c1_bk = (const float*)d_in[7];
    const float* c1_Wv = (const float*)d_in[8];  const float* c1_bv = (const float*)d_in[9];
    const float* c1_Ws = (const float*)d_in[10]; const float* c1_bs = (const float*)d_in[11];
    const float* c2_Wq = (const float*)d_in[12]; const float* c2_bq = (const float*)d_in[13];
    const float* c2_Wk = (const float*)d_in[14]; const float* c2_bk = (const float*)d_in[15];
    const float* c2_Wv = (const float*)d_in[16]; const float* c2_bv = (const float*)d_in[17];
    const float* c2_Ws = (const float*)d_in[18]; const float* c2_bs = (const float*)d_in[19];
    const float* g_W1 = (const float*)d_in[20]; const float* g_b1 = (const float*)d_in[21];
    const float* g_W2 = (const float*)d_in[22]; const float* g_b2 = (const float*)d_in[23];
    const float* h_W1 = (const float*)d_in[24]; const float* h_b1 = (const float*)d_in[25];
    const float* h_W2 = (const float*)d_in[26]; const float* h_b2 = (const float*)d_in[27];
    float* out = (float*)d_out;

    const int* srcp = eidx;
    const int* dstp = eidx + N_EDGES;

    // ---- workspace layout ----
    char* base = (char*)d_ws;
    uchar_t*  kvb  = (uchar_t*)base;  base += (size_t)N_NODES * 512;
    uchar_t*  qb8  = (uchar_t*)base;  base += (size_t)N_NODES * 256;
    ushort_t* skipb = (ushort_t*)base; base += (size_t)N_NODES * HIDDEN * 2;
    ushort_t* h1b  = (ushort_t*)base; base += (size_t)N_NODES * HIDDEN * 2;
    float*    h2   = (float*)base;    base += (size_t)N_NODES * HIDDEN * 4;
    ushort_t* Wt1  = (ushort_t*)base; base += (size_t)IN_CH * QKV_COLS * 2;
    ushort_t* Wt2  = (ushort_t*)base; base += (size_t)HIDDEN * QKV_COLS * 2;
    float*    bcat1 = (float*)base;   base += QKV_COLS * 4;
    float*    bcat2 = (float*)base;   base += QKV_COLS * 4;
    int* ib = (int*)base;
    size_t oi = 0;
    int* deg    = ib + oi; oi += N_NODES;
    int* incl   = ib + oi; oi += N_NODES;
    int* bsums  = ib + oi; oi += 64;
    int* rowptr = ib + oi; oi += N_NODES + 4;
    int* cur    = ib + oi; oi += N_NODES;
    int* colb   = ib + oi; oi += N_EDGES;

    const int NB1 = (N_NODES + 1023) / 1024;   // 49
    const int NBS = (N_NODES + 255) / 256;     // 196
    const int EB  = (N_EDGES + 255) / 256;     // 3125

    const int RB = (N_NODES + 127) / 128;      // 391
    const int GG = 8 * 13 * ((RB + 7) / 8);    // 5096
    dim3 attn_block(64, 4);
    int attn_grid = (N_NODES + 3) / 4;         // 12500

    // ---- CSR + weight prep ----
    hipMemsetAsync(deg, 0, N_NODES * sizeof(int), stream);
    prep2<<<PREP_BLOCKS, 256, 0, stream>>>(
        c1_Wq, c1_Wk, c1_Wv, c1_Ws, c1_bq, c1_bk, c1_bv, c1_bs,
        c2_Wq, c2_Wk, c2_Wv, c2_Ws, c2_bq, c2_bk, c2_bv, c2_bs,
        Wt1, Wt2, bcat1, bcat2, dstp, deg);
    scan1<<<NB1, 1024, 0, stream>>>(deg, incl, bsums, N_NODES);
    scan3f<<<NBS, 256, 0, stream>>>(deg, incl, bsums, rowptr, cur, N_NODES);
    fill_col<<<EB, 256, 0, stream>>>(srcp, dstp, cur, colb);

    // ---- conv1 (A = x fp32, cast in-register) ----
    gemm_v8<IN_CH, true><<<GG, 256, 0, stream>>>(x, Wt1, bcat1, qb8, kvb, skipb, N_NODES, RB);
    attn_agg7<true><<<attn_grid, attn_block, 0, stream>>>(qb8, kvb, skipb, rowptr, colb, h1b);

    // ---- conv2 (A = h1b bf16) ----
    gemm_v8<HIDDEN, false><<<GG, 256, 0, stream>>>(h1b, Wt2, bcat2, qb8, kvb, skipb, N_NODES, RB);
    attn_agg7<false><<<attn_grid, attn_block, 0, stream>>>(qb8, kvb, skipb, rowptr, colb, h2);

    // ---- pool + head fused ----
    pool_head<<<N_GRAPHS, 256, 0, stream>>>(h2, batch, gfeats,
                                            g_W1, g_b1, g_W2, g_b2,
                                            h_W1, h_b1, h_W2, h_b2, out);
}

// Round 11
// 448.485 us; speedup vs baseline: 1.1067x; 1.1067x over previous
//
#include <hip/hip_runtime.h>
#include <hip/hip_bf16.h>
#include <math.h>

#define N_NODES   50000
#define N_EDGES   800000
#define N_GRAPHS  64
#define IN_CH     128
#define GLOBAL_DIM 256
#define HIDDEN    64
#define HEADS     4
#define N_CLASSES 10
#define QKV_COLS  832   // 256 q | 256 k | 256 v | 64 skip

typedef unsigned short ushort_t;
typedef unsigned int uint_t;
typedef unsigned char uchar_t;
typedef __attribute__((ext_vector_type(8))) short short8;
typedef __attribute__((ext_vector_type(4))) float floatx4;
typedef __attribute__((ext_vector_type(2))) float floatx2;

// ---------------------------------------------------------------------------
// helpers
// ---------------------------------------------------------------------------
__device__ __forceinline__ ushort_t bf16rne(float f) {
    uint_t b = __float_as_uint(f);
    b += 0x7fffu + ((b >> 16) & 1u);
    return (ushort_t)(b >> 16);
}
__device__ __forceinline__ float4 bf4_unpack(uint_t lo, uint_t hi) {
    float4 f;
    f.x = __uint_as_float(lo << 16);
    f.y = __uint_as_float(lo & 0xffff0000u);
    f.z = __uint_as_float(hi << 16);
    f.w = __uint_as_float(hi & 0xffff0000u);
    return f;
}
__device__ __forceinline__ uchar_t fp8e4m3(float f) {
    int v = __builtin_amdgcn_cvt_pk_fp8_f32(f, 0.f, 0, false);
    return (uchar_t)(v & 0xff);
}
__device__ __forceinline__ short8 pack_bf8(float4 a, float4 b) {
    union { short8 s; ushort_t u[8]; } r;
    r.u[0] = bf16rne(a.x); r.u[1] = bf16rne(a.y);
    r.u[2] = bf16rne(a.z); r.u[3] = bf16rne(a.w);
    r.u[4] = bf16rne(b.x); r.u[5] = bf16rne(b.y);
    r.u[6] = bf16rne(b.z); r.u[7] = bf16rne(b.w);
    return r.s;
}

// ---------------------------------------------------------------------------
// PREP: concat both layers' weights  ||  count_deg
// ---------------------------------------------------------------------------
#define PREP_CONC_B  624
#define PREP_CNT_B   1024
#define PREP_BLOCKS  (PREP_CONC_B + PREP_CNT_B)

__global__ __launch_bounds__(256) void prep2(
        const float* __restrict__ W1q, const float* __restrict__ W1k,
        const float* __restrict__ W1v, const float* __restrict__ W1s,
        const float* __restrict__ b1q, const float* __restrict__ b1k,
        const float* __restrict__ b1v, const float* __restrict__ b1s,
        const float* __restrict__ W2q, const float* __restrict__ W2k,
        const float* __restrict__ W2v, const float* __restrict__ W2s,
        const float* __restrict__ b2q, const float* __restrict__ b2k,
        const float* __restrict__ b2v, const float* __restrict__ b2s,
        ushort_t* __restrict__ Wt1, ushort_t* __restrict__ Wt2,
        float* __restrict__ bcat1, float* __restrict__ bcat2,
        const int* __restrict__ dst, int* __restrict__ deg) {
    int b = blockIdx.x, t = threadIdx.x;
    if (b < PREP_CONC_B) {
        int idx = b * 256 + t;
        const int T1 = IN_CH * QKV_COLS;
        const int T2 = HIDDEN * QKV_COLS;
        if (idx < T1) {
            int c = idx / IN_CH, k = idx % IN_CH;
            float v;
            if (c < 256)      v = W1q[k * 256 + c];
            else if (c < 512) v = W1k[k * 256 + (c - 256)];
            else if (c < 768) v = W1v[k * 256 + (c - 512)];
            else              v = W1s[k * 64  + (c - 768)];
            Wt1[idx] = bf16rne(v);
        } else if (idx < T1 + T2) {
            int i2 = idx - T1;
            int c = i2 / HIDDEN, k = i2 % HIDDEN;
            float v;
            if (c < 256)      v = W2q[k * 256 + c];
            else if (c < 512) v = W2k[k * 256 + (c - 256)];
            else if (c < 768) v = W2v[k * 256 + (c - 512)];
            else              v = W2s[k * 64  + (c - 768)];
            Wt2[i2] = bf16rne(v);
        }
        if (idx < QKV_COLS) {
            float bb, b2;
            if (idx < 256)      { bb = b1q[idx];       b2 = b2q[idx]; }
            else if (idx < 512) { bb = b1k[idx - 256]; b2 = b2k[idx - 256]; }
            else if (idx < 768) { bb = b1v[idx - 512]; b2 = b2v[idx - 512]; }
            else                { bb = b1s[idx - 768]; b2 = b2s[idx - 768]; }
            bcat1[idx] = bb;
            bcat2[idx] = b2;
        }
    } else {
        int idx = (b - PREP_CONC_B) * 256 + t;
        for (int e = idx; e < N_EDGES; e += PREP_CNT_B * 256)
            atomicAdd(&deg[dst[e]], 1);
    }
}

// ---------------------------------------------------------------------------
// scans + fill
// ---------------------------------------------------------------------------
__global__ void scan1(const int* __restrict__ deg, int* __restrict__ incl,
                      int* __restrict__ bsums, int n) {
    __shared__ int sh[1024];
    int t = threadIdx.x;
    int gid = blockIdx.x * 1024 + t;
    int v = (gid < n) ? deg[gid] : 0;
    sh[t] = v;
    __syncthreads();
    for (int off = 1; off < 1024; off <<= 1) {
        int tmp = (t >= off) ? sh[t - off] : 0;
        __syncthreads();
        sh[t] += tmp;
        __syncthreads();
    }
    if (gid < n) incl[gid] = sh[t];
    if (t == 1023) bsums[blockIdx.x] = sh[1023];
}

__global__ void scan3f(const int* __restrict__ deg, const int* __restrict__ incl,
                       const int* __restrict__ bsums, int* __restrict__ rowptr,
                       int* __restrict__ cur, int n) {
    __shared__ int sb;
    int t = threadIdx.x;
    int b = (int)(blockIdx.x >> 2);
    if (t < 64) {
        int v = (t < b) ? bsums[t] : 0;
#pragma unroll
        for (int off = 1; off < 64; off <<= 1) v += __shfl_xor(v, off);
        if (t == 0) sb = v;
    }
    __syncthreads();
    int gid = blockIdx.x * 256 + t;
    if (gid < n) {
        int in = incl[gid] + sb;
        int ex = in - deg[gid];
        rowptr[gid] = ex;
        cur[gid] = ex;
        if (gid == n - 1) rowptr[n] = in;
    }
}

__global__ void fill_col(const int* __restrict__ src, const int* __restrict__ dst,
                         int* __restrict__ cur, int* __restrict__ col) {
    int e = blockIdx.x * 256 + threadIdx.x;
    if (e < N_EDGES) {
        int d = dst[e];
        int pos = atomicAdd(&cur[d], 1);
        col[pos] = src[e];
    }
}

// ---------------------------------------------------------------------------
// GEMM v9 = round-7 winner (B staged in LDS, A fragments direct from global)
// + A_FP32 template (conv1 reads x fp32, casts in-register).
// XCD-swizzled 1D grid; epilogue via LDS tile, coalesced wide stores.
// Outputs: ct 0-3 q fp8 | ct 4-7 k fp8 | ct 8-11 v fp8 | ct 12 skip bf16.
// LDS: max(Bs K=128: 64*136*2 = 17408, fp8 tile 10240, bf16 tile 17408).
// ---------------------------------------------------------------------------
template <int K, bool A_FP32>
__global__ __launch_bounds__(256) void gemm_v9(const void* __restrict__ Av,
                                               const ushort_t* __restrict__ Wt,
                                               const float* __restrict__ bias,
                                               uchar_t* __restrict__ qb8,
                                               uchar_t* __restrict__ kvb,
                                               ushort_t* __restrict__ skipb,
                                               int N, int RB) {
    constexpr int KP = K + 8;
    constexpr int C8 = K / 8;
    __shared__ uchar_t smem[17408] __attribute__((aligned(16)));
    ushort_t* Bs = (ushort_t*)smem;

    const int t = threadIdx.x;
    const int idx0 = (int)blockIdx.x;
    const int xcd = idx0 & 7;
    const int j = idx0 >> 3;
    const int ct = j % 13;
    const int strip = (j / 13) * 8 + xcd;
    if (strip >= RB) return;
    const int base_r = strip * 128;
    const int base_c = ct * 64;

    // ---- stage B tile (64 cols of Wt) into LDS ----
#pragma unroll
    for (int i = 0; i < (64 * C8) / 256; ++i) {
        int ii = t + i * 256;
        int n = ii / C8, c = ii % C8;
        *(uint4*)(Bs + n * KP + c * 8) =
            *(const uint4*)(Wt + (size_t)(base_c + n) * K + c * 8);
    }

    const int wave = t >> 6, lane = t & 63;
    const int quad = lane >> 4, m16 = lane & 15;

    // ---- A fragments direct from global (pre-loop, latency paid once) ----
    int arow0 = base_r + wave * 32 + m16;
    int arow1 = arow0 + 16;
    int cr0 = arow0 < N ? arow0 : N - 1;
    int cr1 = arow1 < N ? arow1 : N - 1;
    short8 a0[K / 32], a1[K / 32];
    if (A_FP32) {
        const float* A = (const float*)Av;
        const float* Ar0 = A + (size_t)cr0 * K + quad * 8;
        const float* Ar1 = A + (size_t)cr1 * K + quad * 8;
#pragma unroll
        for (int kc = 0; kc < K / 32; ++kc) {
            float4 f0 = *(const float4*)(Ar0 + kc * 32);
            float4 f1 = *(const float4*)(Ar0 + kc * 32 + 4);
            a0[kc] = pack_bf8(f0, f1);
            float4 g0 = *(const float4*)(Ar1 + kc * 32);
            float4 g1 = *(const float4*)(Ar1 + kc * 32 + 4);
            a1[kc] = pack_bf8(g0, g1);
        }
    } else {
        const ushort_t* A = (const ushort_t*)Av;
        const ushort_t* Ar0 = A + (size_t)cr0 * K + quad * 8;
        const ushort_t* Ar1 = A + (size_t)cr1 * K + quad * 8;
#pragma unroll
        for (int kc = 0; kc < K / 32; ++kc) {
            a0[kc] = *(const short8*)(Ar0 + kc * 32);
            a1[kc] = *(const short8*)(Ar1 + kc * 32);
        }
    }
    __syncthreads();   // Bs ready

    floatx4 acc[2][4];
#pragma unroll
    for (int rt = 0; rt < 2; ++rt)
#pragma unroll
        for (int c2 = 0; c2 < 4; ++c2) acc[rt][c2] = (floatx4){0.f, 0.f, 0.f, 0.f};
#pragma unroll
    for (int kc = 0; kc < K / 32; ++kc) {
        int ko = kc * 32 + quad * 8;
#pragma unroll
        for (int c2 = 0; c2 < 4; ++c2) {
            short8 b = *(const short8*)(Bs + (c2 * 16 + m16) * KP + ko);
            acc[0][c2] = __builtin_amdgcn_mfma_f32_16x16x32_bf16(a0[kc], b, acc[0][c2], 0, 0, 0);
            acc[1][c2] = __builtin_amdgcn_mfma_f32_16x16x32_bf16(a1[kc], b, acc[1][c2], 0, 0, 0);
        }
    }

    float bb[4];
#pragma unroll
    for (int c2 = 0; c2 < 4; ++c2) bb[c2] = bias[base_c + c2 * 16 + m16];
#pragma unroll
    for (int rt = 0; rt < 2; ++rt)
#pragma unroll
        for (int c2 = 0; c2 < 4; ++c2)
#pragma unroll
            for (int r = 0; r < 4; ++r) acc[rt][c2][r] += bb[c2];

    __syncthreads();   // Bs free -> reuse for epilogue tile

    // lane elem (rt,c2,r): row_l = wave*32+rt*16+quad*4+r, col_l = c2*16+m16
    if (ct < 12) {
        uchar_t* ep = smem;    // fp8 tile [128][stride 80]
#pragma unroll
        for (int c2 = 0; c2 < 4; ++c2) {
            int col_l = c2 * 16 + m16;
#pragma unroll
            for (int rt = 0; rt < 2; ++rt)
#pragma unroll
                for (int r = 0; r < 4; ++r)
                    ep[(wave * 32 + rt * 16 + quad * 4 + r) * 80 + col_l] =
                        fp8e4m3(acc[rt][c2][r]);
        }
        __syncthreads();
        uchar_t* dstbase;
        size_t rstride;
        int off;
        if (ct < 4)      { dstbase = qb8; rstride = 256; off = base_c; }
        else if (ct < 8) { dstbase = kvb; rstride = 512; off = base_c - 256; }
        else             { dstbase = kvb; rstride = 512; off = 256 + (base_c - 512); }
#pragma unroll
        for (int i = 0; i < 2; ++i) {
            int ii = t + i * 256;
            int row = ii >> 2, ch = ii & 3;
            int gr = base_r + row;
            if (gr < N)
                *(uint4*)(dstbase + (size_t)gr * rstride + off + ch * 16) =
                    *(const uint4*)(ep + row * 80 + ch * 16);
        }
    } else {
        // skip tile: bf16 [128][stride 68], single pass (17408 B)
        ushort_t* ep = (ushort_t*)smem;
#pragma unroll
        for (int c2 = 0; c2 < 4; ++c2) {
            int col_l = c2 * 16 + m16;
#pragma unroll
            for (int rt = 0; rt < 2; ++rt)
#pragma unroll
                for (int r = 0; r < 4; ++r)
                    ep[(wave * 32 + rt * 16 + quad * 4 + r) * 68 + col_l] =
                        bf16rne(acc[rt][c2][r]);
        }
        __syncthreads();
#pragma unroll
        for (int i = 0; i < 4; ++i) {
            int ii = t + i * 256;
            int row = ii >> 3, ch = ii & 7;
            int gr = base_r + row;
            if (gr < N)
                *(uint4*)(skipb + (size_t)gr * 64 + ch * 8) =
                    *(const uint4*)(ep + row * 68 + ch * 8);
        }
    }
}

// ---------------------------------------------------------------------------
// attn v7: packed-fp32 math; q pre-scaled by 1/8; head-mean 0.25 folded in 1/z.
// kvb: node*512 + [0:256)=k fp8, [256:512)=v fp8. sl=lane&31 owns 8 dims.
// ---------------------------------------------------------------------------
__device__ __forceinline__ void edge_step3(uint2 k8, uint2 v8, const floatx2* qp,
                                           float& z, floatx2* acp) {
    floatx2 dp = qp[0] * __builtin_amdgcn_cvt_pk_f32_fp8(k8.x, false);
    dp += qp[1] * __builtin_amdgcn_cvt_pk_f32_fp8(k8.x, true);
    dp += qp[2] * __builtin_amdgcn_cvt_pk_f32_fp8(k8.y, false);
    dp += qp[3] * __builtin_amdgcn_cvt_pk_f32_fp8(k8.y, true);
    float d = dp[0] + dp[1];
    d += __shfl_xor(d, 1);
    d += __shfl_xor(d, 2);
    d += __shfl_xor(d, 4);
    float p = __expf(d);           // q already scaled by 1/8
    z += p;
    floatx2 pp = {p, p};
    acp[0] += pp * __builtin_amdgcn_cvt_pk_f32_fp8(v8.x, false);
    acp[1] += pp * __builtin_amdgcn_cvt_pk_f32_fp8(v8.x, true);
    acp[2] += pp * __builtin_amdgcn_cvt_pk_f32_fp8(v8.y, false);
    acp[3] += pp * __builtin_amdgcn_cvt_pk_f32_fp8(v8.y, true);
}

template <bool OUT_BF16>
__global__ __launch_bounds__(256) void attn_agg7(const uchar_t* __restrict__ qb8,
                                                 const uchar_t* __restrict__ kvb,
                                                 const ushort_t* __restrict__ skipb,
                                                 const int* __restrict__ rowptr,
                                                 const int* __restrict__ col,
                                                 void* __restrict__ hout) {
    int node = blockIdx.x * 4 + threadIdx.y;
    if (node >= N_NODES) return;
    int lane = threadIdx.x;
    int half = lane >> 5, sl = lane & 31;
    uint2 qd = *(const uint2*)(qb8 + (size_t)node * 256 + sl * 8);
    const floatx2 s8 = {0.125f, 0.125f};
    floatx2 qp[4];
    qp[0] = s8 * __builtin_amdgcn_cvt_pk_f32_fp8(qd.x, false);
    qp[1] = s8 * __builtin_amdgcn_cvt_pk_f32_fp8(qd.x, true);
    qp[2] = s8 * __builtin_amdgcn_cvt_pk_f32_fp8(qd.y, false);
    qp[3] = s8 * __builtin_amdgcn_cvt_pk_f32_fp8(qd.y, true);
    floatx2 acp[4];
    acp[0] = (floatx2){0.f, 0.f}; acp[1] = (floatx2){0.f, 0.f};
    acp[2] = (floatx2){0.f, 0.f}; acp[3] = (floatx2){0.f, 0.f};
    float z = 0.f;
    int beg = rowptr[node], end = rowptr[node + 1];
    int e = beg + half;
    const size_t loff = (size_t)sl * 8;
    for (; e + 6 < end; e += 8) {
        const uchar_t* p0 = kvb + (size_t)col[e]     * 512 + loff;
        const uchar_t* p1 = kvb + (size_t)col[e + 2] * 512 + loff;
        const uchar_t* p2 = kvb + (size_t)col[e + 4] * 512 + loff;
        const uchar_t* p3 = kvb + (size_t)col[e + 6] * 512 + loff;
        uint2 k0 = *(const uint2*)p0, v0 = *(const uint2*)(p0 + 256);
        uint2 k1 = *(const uint2*)p1, v1 = *(const uint2*)(p1 + 256);
        uint2 k2 = *(const uint2*)p2, v2 = *(const uint2*)(p2 + 256);
        uint2 k3 = *(const uint2*)p3, v3 = *(const uint2*)(p3 + 256);
        edge_step3(k0, v0, qp, z, acp);
        edge_step3(k1, v1, qp, z, acp);
        edge_step3(k2, v2, qp, z, acp);
        edge_step3(k3, v3, qp, z, acp);
    }
    for (; e < end; e += 2) {
        const uchar_t* p0 = kvb + (size_t)col[e] * 512 + loff;
        uint2 k0 = *(const uint2*)p0, v0 = *(const uint2*)(p0 + 256);
        edge_step3(k0, v0, qp, z, acp);
    }
    z += __shfl_xor(z, 32);
    float ac[8] = {acp[0][0], acp[0][1], acp[1][0], acp[1][1],
                   acp[2][0], acp[2][1], acp[3][0], acp[3][1]};
#pragma unroll
    for (int i = 0; i < 8; ++i) ac[i] += __shfl_xor(ac[i], 32);
    float inv = (z > 0.f) ? (0.25f / z) : 0.f;   // head-mean folded in
#pragma unroll
    for (int i = 0; i < 8; ++i) ac[i] *= inv;
#pragma unroll
    for (int i = 0; i < 8; ++i) {
        ac[i] += __shfl_xor(ac[i], 8);
        ac[i] += __shfl_xor(ac[i], 16);
    }
    if (lane < 8) {
        uint4 su = *(const uint4*)(skipb + (size_t)node * 64 + lane * 8);
        float4 s0 = bf4_unpack(su.x, su.y);
        float4 s1 = bf4_unpack(su.z, su.w);
        float o0 = fmaxf(ac[0] + s0.x, 0.f);
        float o1 = fmaxf(ac[1] + s0.y, 0.f);
        float o2 = fmaxf(ac[2] + s0.z, 0.f);
        float o3 = fmaxf(ac[3] + s0.w, 0.f);
        float o4 = fmaxf(ac[4] + s1.x, 0.f);
        float o5 = fmaxf(ac[5] + s1.y, 0.f);
        float o6 = fmaxf(ac[6] + s1.z, 0.f);
        float o7 = fmaxf(ac[7] + s1.w, 0.f);
        if (OUT_BF16) {
            uint4 u;
            u.x = (uint_t)bf16rne(o0) | ((uint_t)bf16rne(o1) << 16);
            u.y = (uint_t)bf16rne(o2) | ((uint_t)bf16rne(o3) << 16);
            u.z = (uint_t)bf16rne(o4) | ((uint_t)bf16rne(o5) << 16);
            u.w = (uint_t)bf16rne(o6) | ((uint_t)bf16rne(o7) << 16);
            *(uint4*)((ushort_t*)hout + (size_t)node * HIDDEN + lane * 8) = u;
        } else {
            float* op = (float*)hout + (size_t)node * HIDDEN + lane * 8;
            *(float4*)(op)     = make_float4(o0, o1, o2, o3);
            *(float4*)(op + 4) = make_float4(o4, o5, o6, o7);
        }
    }
}

// ---------------------------------------------------------------------------
// pool + head fused: one 256-thread block per graph
// ---------------------------------------------------------------------------
__global__ __launch_bounds__(256) void pool_head(const float* __restrict__ h,
                                                 const int* __restrict__ batch,
                                                 const float* __restrict__ gf,
                                                 const float* __restrict__ gW1, const float* __restrict__ gb1,
                                                 const float* __restrict__ gW2, const float* __restrict__ gb2,
                                                 const float* __restrict__ hW1, const float* __restrict__ hb1,
                                                 const float* __restrict__ hW2, const float* __restrict__ hb2,
                                                 float* __restrict__ out) {
    int g = blockIdx.x;
    int lo = 0, hi = N_NODES;
    while (lo < hi) { int mid = (lo + hi) >> 1; if (batch[mid] < g) lo = mid + 1; else hi = mid; }
    int start = lo;
    hi = N_NODES;
    while (lo < hi) { int mid = (lo + hi) >> 1; if (batch[mid] < g + 1) lo = mid + 1; else hi = mid; }
    int end = lo;
    int t = threadIdx.x;
    int d = t & 63, chunk = t >> 6;
    float acc = 0.f;
    for (int n = start + chunk; n < end; n += 4) acc += h[(size_t)n * HIDDEN + d];
    __shared__ float sh[256];
    __shared__ float gfs[GLOBAL_DIM];
    __shared__ float fused[2 * HIDDEN];
    __shared__ float g1[HIDDEN];
    __shared__ float h1s[HIDDEN];
    sh[t] = acc;
    gfs[t] = gf[(size_t)g * GLOBAL_DIM + t];
    __syncthreads();
    if (chunk == 0) {
        float cnt = fmaxf((float)(end - start), 1.0f);
        fused[d] = (sh[d] + sh[64 + d] + sh[128 + d] + sh[192 + d]) / cnt;
        float a = gb1[d];
        for (int k = 0; k < GLOBAL_DIM; ++k) a = fmaf(gfs[k], gW1[k * HIDDEN + d], a);
        g1[d] = fmaxf(a, 0.f);
    }
    __syncthreads();
    if (chunk == 0) {
        float a = gb2[d];
        for (int k = 0; k < HIDDEN; ++k) a = fmaf(g1[k], gW2[k * HIDDEN + d], a);
        fused[HIDDEN + d] = fmaxf(a, 0.f);
    }
    __syncthreads();
    if (chunk == 0) {
        float a = hb1[d];
        for (int k = 0; k < 2 * HIDDEN; ++k) a = fmaf(fused[k], hW1[k * HIDDEN + d], a);
        h1s[d] = fmaxf(a, 0.f);
    }
    __syncthreads();
    if (t < N_CLASSES) {
        float o = hb2[t];
        for (int k = 0; k < HIDDEN; ++k) o = fmaf(h1s[k], hW2[k * N_CLASSES + t], o);
        out[(size_t)g * N_CLASSES + t] = o;
    }
}

// ---------------------------------------------------------------------------
extern "C" void kernel_launch(void* const* d_in, const int* in_sizes, int n_in,
                              void* d_out, int out_size, void* d_ws, size_t ws_size,
                              hipStream_t stream) {
    const float* x        = (const float*)d_in[0];
    const int*   eidx     = (const int*)d_in[1];
    const int*   batch    = (const int*)d_in[2];
    const float* gfeats   = (const float*)d_in[3];
    const float* c1_Wq = (const float*)d_in[4];  const float* c1_bq = (const float*)d_in[5];
    const float* c1_Wk = (const float*)d_in[6];  const float* c1_bk = (const float*)d_in[7];
    const float* c1_Wv = (const float*)d_in[8];  const float* c1_bv = (const float*)d_in[9];
    const float* c1_Ws = (const float*)d_in[10]; const float* c1_bs = (const float*)d_in[11];
    const float* c2_Wq = (const float*)d_in[12]; const float* c2_bq = (const float*)d_in[13];
    const float* c2_Wk = (const float*)d_in[14]; const float* c2_bk = (const float*)d_in[15];
    const float* c2_Wv = (const float*)d_in[16]; const float* c2_bv = (const float*)d_in[17];
    const float* c2_Ws = (const float*)d_in[18]; const float* c2_bs = (const float*)d_in[19];
    const float* g_W1 = (const float*)d_in[20]; const float* g_b1 = (const float*)d_in[21];
    const float* g_W2 = (const float*)d_in[22]; const float* g_b2 = (const float*)d_in[23];
    const float* h_W1 = (const float*)d_in[24]; const float* h_b1 = (const float*)d_in[25];
    const float* h_W2 = (const float*)d_in[26]; const float* h_b2 = (const float*)d_in[27];
    float* out = (float*)d_out;

    const int* srcp = eidx;
    const int* dstp = eidx + N_EDGES;

    // ---- workspace layout ----
    char* base = (char*)d_ws;
    uchar_t*  kvb  = (uchar_t*)base;  base += (size_t)N_NODES * 512;
    uchar_t*  qb8  = (uchar_t*)base;  base += (size_t)N_NODES * 256;
    ushort_t* skipb = (ushort_t*)base; base += (size_t)N_NODES * HIDDEN * 2;
    ushort_t* h1b  = (ushort_t*)base; base += (size_t)N_NODES * HIDDEN * 2;
    float*    h2   = (float*)base;    base += (size_t)N_NODES * HIDDEN * 4;
    ushort_t* Wt1  = (ushort_t*)base; base += (size_t)IN_CH * QKV_COLS * 2;
    ushort_t* Wt2  = (ushort_t*)base; base += (size_t)HIDDEN * QKV_COLS * 2;
    float*    bcat1 = (float*)base;   base += QKV_COLS * 4;
    float*    bcat2 = (float*)base;   base += QKV_COLS * 4;
    int* ib = (int*)base;
    size_t oi = 0;
    int* deg    = ib + oi; oi += N_NODES;
    int* incl   = ib + oi; oi += N_NODES;
    int* bsums  = ib + oi; oi += 64;
    int* rowptr = ib + oi; oi += N_NODES + 4;
    int* cur    = ib + oi; oi += N_NODES;
    int* colb   = ib + oi; oi += N_EDGES;

    const int NB1 = (N_NODES + 1023) / 1024;   // 49
    const int NBS = (N_NODES + 255) / 256;     // 196
    const int EB  = (N_EDGES + 255) / 256;     // 3125

    const int RB = (N_NODES + 127) / 128;      // 391
    const int GG = 8 * 13 * ((RB + 7) / 8);    // 5096
    dim3 attn_block(64, 4);
    int attn_grid = (N_NODES + 3) / 4;         // 12500

    // ---- CSR + weight prep ----
    hipMemsetAsync(deg, 0, N_NODES * sizeof(int), stream);
    prep2<<<PREP_BLOCKS, 256, 0, stream>>>(
        c1_Wq, c1_Wk, c1_Wv, c1_Ws, c1_bq, c1_bk, c1_bv, c1_bs,
        c2_Wq, c2_Wk, c2_Wv, c2_Ws, c2_bq, c2_bk, c2_bv, c2_bs,
        Wt1, Wt2, bcat1, bcat2, dstp, deg);
    scan1<<<NB1, 1024, 0, stream>>>(deg, incl, bsums, N_NODES);
    scan3f<<<NBS, 256, 0, stream>>>(deg, incl, bsums, rowptr, cur, N_NODES);
    fill_col<<<EB, 256, 0, stream>>>(srcp, dstp, cur, colb);

    // ---- conv1 (A = x fp32, cast in-register; B staged in LDS) ----
    gemm_v9<IN_CH, true><<<GG, 256, 0, stream>>>(x, Wt1, bcat1, qb8, kvb, skipb, N_NODES, RB);
    attn_agg7<true><<<attn_grid, attn_block, 0, stream>>>(qb8, kvb, skipb, rowptr, colb, h1b);

    // ---- conv2 (A = h1b bf16) ----
    gemm_v9<HIDDEN, false><<<GG, 256, 0, stream>>>(h1b, Wt2, bcat2, qb8, kvb, skipb, N_NODES, RB);
    attn_agg7<false><<<attn_grid, attn_block, 0, stream>>>(qb8, kvb, skipb, rowptr, colb, h2);

    // ---- pool + head fused ----
    pool_head<<<N_GRAPHS, 256, 0, stream>>>(h2, batch, gfeats,
                                            g_W1, g_b1, g_W2, g_b2,
                                            h_W1, h_b1, h_W2, h_b2, out);
}

// Round 12
// 419.502 us; speedup vs baseline: 1.1832x; 1.0691x over previous
//
#include <hip/hip_runtime.h>
#include <hip/hip_bf16.h>
#include <math.h>

#define N_NODES   50000
#define N_EDGES   800000
#define N_GRAPHS  64
#define IN_CH     128
#define GLOBAL_DIM 256
#define HIDDEN    64
#define HEADS     4
#define N_CLASSES 10
#define QKV_COLS  832   // 256 q | 256 k | 256 v | 64 skip

typedef unsigned short ushort_t;
typedef unsigned int uint_t;
typedef unsigned char uchar_t;
typedef __attribute__((ext_vector_type(8))) short short8;
typedef __attribute__((ext_vector_type(4))) float floatx4;
typedef __attribute__((ext_vector_type(2))) float floatx2;

// ---------------------------------------------------------------------------
// helpers
// ---------------------------------------------------------------------------
__device__ __forceinline__ ushort_t bf16rne(float f) {
    uint_t b = __float_as_uint(f);
    b += 0x7fffu + ((b >> 16) & 1u);
    return (ushort_t)(b >> 16);
}
__device__ __forceinline__ float4 bf4_unpack(uint_t lo, uint_t hi) {
    float4 f;
    f.x = __uint_as_float(lo << 16);
    f.y = __uint_as_float(lo & 0xffff0000u);
    f.z = __uint_as_float(hi << 16);
    f.w = __uint_as_float(hi & 0xffff0000u);
    return f;
}
__device__ __forceinline__ uchar_t fp8e4m3(float f) {
    int v = __builtin_amdgcn_cvt_pk_fp8_f32(f, 0.f, 0, false);
    return (uchar_t)(v & 0xff);
}
__device__ __forceinline__ short8 pack_bf8(float4 a, float4 b) {
    union { short8 s; ushort_t u[8]; } r;
    r.u[0] = bf16rne(a.x); r.u[1] = bf16rne(a.y);
    r.u[2] = bf16rne(a.z); r.u[3] = bf16rne(a.w);
    r.u[4] = bf16rne(b.x); r.u[5] = bf16rne(b.y);
    r.u[6] = bf16rne(b.z); r.u[7] = bf16rne(b.w);
    return r.s;
}
__device__ __forceinline__ void graph_range(const int* __restrict__ batch, int g,
                                            int& start, int& end) {
    int lo = 0, hi = N_NODES;
    while (lo < hi) { int mid = (lo + hi) >> 1; if (batch[mid] < g) lo = mid + 1; else hi = mid; }
    start = lo;
    hi = N_NODES;
    while (lo < hi) { int mid = (lo + hi) >> 1; if (batch[mid] < g + 1) lo = mid + 1; else hi = mid; }
    end = lo;
}

// ---------------------------------------------------------------------------
// PREP: concat both layers' weights  ||  count_deg
// ---------------------------------------------------------------------------
#define PREP_CONC_B  624
#define PREP_CNT_B   1024
#define PREP_BLOCKS  (PREP_CONC_B + PREP_CNT_B)

__global__ __launch_bounds__(256) void prep2(
        const float* __restrict__ W1q, const float* __restrict__ W1k,
        const float* __restrict__ W1v, const float* __restrict__ W1s,
        const float* __restrict__ b1q, const float* __restrict__ b1k,
        const float* __restrict__ b1v, const float* __restrict__ b1s,
        const float* __restrict__ W2q, const float* __restrict__ W2k,
        const float* __restrict__ W2v, const float* __restrict__ W2s,
        const float* __restrict__ b2q, const float* __restrict__ b2k,
        const float* __restrict__ b2v, const float* __restrict__ b2s,
        ushort_t* __restrict__ Wt1, ushort_t* __restrict__ Wt2,
        float* __restrict__ bcat1, float* __restrict__ bcat2,
        const int* __restrict__ dst, int* __restrict__ deg) {
    int b = blockIdx.x, t = threadIdx.x;
    if (b < PREP_CONC_B) {
        int idx = b * 256 + t;
        const int T1 = IN_CH * QKV_COLS;
        const int T2 = HIDDEN * QKV_COLS;
        if (idx < T1) {
            int c = idx / IN_CH, k = idx % IN_CH;
            float v;
            if (c < 256)      v = W1q[k * 256 + c];
            else if (c < 512) v = W1k[k * 256 + (c - 256)];
            else if (c < 768) v = W1v[k * 256 + (c - 512)];
            else              v = W1s[k * 64  + (c - 768)];
            Wt1[idx] = bf16rne(v);
        } else if (idx < T1 + T2) {
            int i2 = idx - T1;
            int c = i2 / HIDDEN, k = i2 % HIDDEN;
            float v;
            if (c < 256)      v = W2q[k * 256 + c];
            else if (c < 512) v = W2k[k * 256 + (c - 256)];
            else if (c < 768) v = W2v[k * 256 + (c - 512)];
            else              v = W2s[k * 64  + (c - 768)];
            Wt2[i2] = bf16rne(v);
        }
        if (idx < QKV_COLS) {
            float bb, b2;
            if (idx < 256)      { bb = b1q[idx];       b2 = b2q[idx]; }
            else if (idx < 512) { bb = b1k[idx - 256]; b2 = b2k[idx - 256]; }
            else if (idx < 768) { bb = b1v[idx - 512]; b2 = b2v[idx - 512]; }
            else                { bb = b1s[idx - 768]; b2 = b2s[idx - 768]; }
            bcat1[idx] = bb;
            bcat2[idx] = b2;
        }
    } else {
        int idx = (b - PREP_CONC_B) * 256 + t;
        for (int e = idx; e < N_EDGES; e += PREP_CNT_B * 256)
            atomicAdd(&deg[dst[e]], 1);
    }
}

// ---------------------------------------------------------------------------
// scans + fill
// ---------------------------------------------------------------------------
__global__ void scan1(const int* __restrict__ deg, int* __restrict__ incl,
                      int* __restrict__ bsums, int n) {
    __shared__ int sh[1024];
    int t = threadIdx.x;
    int gid = blockIdx.x * 1024 + t;
    int v = (gid < n) ? deg[gid] : 0;
    sh[t] = v;
    __syncthreads();
    for (int off = 1; off < 1024; off <<= 1) {
        int tmp = (t >= off) ? sh[t - off] : 0;
        __syncthreads();
        sh[t] += tmp;
        __syncthreads();
    }
    if (gid < n) incl[gid] = sh[t];
    if (t == 1023) bsums[blockIdx.x] = sh[1023];
}

__global__ void scan3f(const int* __restrict__ deg, const int* __restrict__ incl,
                       const int* __restrict__ bsums, int* __restrict__ rowptr,
                       int* __restrict__ cur, int n) {
    __shared__ int sb;
    int t = threadIdx.x;
    int b = (int)(blockIdx.x >> 2);
    if (t < 64) {
        int v = (t < b) ? bsums[t] : 0;
#pragma unroll
        for (int off = 1; off < 64; off <<= 1) v += __shfl_xor(v, off);
        if (t == 0) sb = v;
    }
    __syncthreads();
    int gid = blockIdx.x * 256 + t;
    if (gid < n) {
        int in = incl[gid] + sb;
        int ex = in - deg[gid];
        rowptr[gid] = ex;
        cur[gid] = ex;
        if (gid == n - 1) rowptr[n] = in;
    }
}

__global__ void fill_col(const int* __restrict__ src, const int* __restrict__ dst,
                         int* __restrict__ cur, int* __restrict__ col) {
    int e = blockIdx.x * 256 + threadIdx.x;
    if (e < N_EDGES) {
        int d = dst[e];
        int pos = atomicAdd(&cur[d], 1);
        col[pos] = src[e];
    }
}

// ---------------------------------------------------------------------------
// GEMM v9 (round-7 winner): B staged in LDS, A fragments direct from global,
// A_FP32 template for conv1. XCD-swizzled 1D grid; LDS-tiled epilogue.
// Outputs: ct 0-3 q fp8 | ct 4-7 k fp8 | ct 8-11 v fp8 | ct 12 skip bf16.
// ---------------------------------------------------------------------------
template <int K, bool A_FP32>
__global__ __launch_bounds__(256) void gemm_v9(const void* __restrict__ Av,
                                               const ushort_t* __restrict__ Wt,
                                               const float* __restrict__ bias,
                                               uchar_t* __restrict__ qb8,
                                               uchar_t* __restrict__ kvb,
                                               ushort_t* __restrict__ skipb,
                                               int N, int RB) {
    constexpr int KP = K + 8;
    constexpr int C8 = K / 8;
    __shared__ uchar_t smem[17408] __attribute__((aligned(16)));
    ushort_t* Bs = (ushort_t*)smem;

    const int t = threadIdx.x;
    const int idx0 = (int)blockIdx.x;
    const int xcd = idx0 & 7;
    const int j = idx0 >> 3;
    const int ct = j % 13;
    const int strip = (j / 13) * 8 + xcd;
    if (strip >= RB) return;
    const int base_r = strip * 128;
    const int base_c = ct * 64;

#pragma unroll
    for (int i = 0; i < (64 * C8) / 256; ++i) {
        int ii = t + i * 256;
        int n = ii / C8, c = ii % C8;
        *(uint4*)(Bs + n * KP + c * 8) =
            *(const uint4*)(Wt + (size_t)(base_c + n) * K + c * 8);
    }

    const int wave = t >> 6, lane = t & 63;
    const int quad = lane >> 4, m16 = lane & 15;

    int arow0 = base_r + wave * 32 + m16;
    int arow1 = arow0 + 16;
    int cr0 = arow0 < N ? arow0 : N - 1;
    int cr1 = arow1 < N ? arow1 : N - 1;
    short8 a0[K / 32], a1[K / 32];
    if (A_FP32) {
        const float* A = (const float*)Av;
        const float* Ar0 = A + (size_t)cr0 * K + quad * 8;
        const float* Ar1 = A + (size_t)cr1 * K + quad * 8;
#pragma unroll
        for (int kc = 0; kc < K / 32; ++kc) {
            float4 f0 = *(const float4*)(Ar0 + kc * 32);
            float4 f1 = *(const float4*)(Ar0 + kc * 32 + 4);
            a0[kc] = pack_bf8(f0, f1);
            float4 g0 = *(const float4*)(Ar1 + kc * 32);
            float4 g1 = *(const float4*)(Ar1 + kc * 32 + 4);
            a1[kc] = pack_bf8(g0, g1);
        }
    } else {
        const ushort_t* A = (const ushort_t*)Av;
        const ushort_t* Ar0 = A + (size_t)cr0 * K + quad * 8;
        const ushort_t* Ar1 = A + (size_t)cr1 * K + quad * 8;
#pragma unroll
        for (int kc = 0; kc < K / 32; ++kc) {
            a0[kc] = *(const short8*)(Ar0 + kc * 32);
            a1[kc] = *(const short8*)(Ar1 + kc * 32);
        }
    }
    __syncthreads();   // Bs ready

    floatx4 acc[2][4];
#pragma unroll
    for (int rt = 0; rt < 2; ++rt)
#pragma unroll
        for (int c2 = 0; c2 < 4; ++c2) acc[rt][c2] = (floatx4){0.f, 0.f, 0.f, 0.f};
#pragma unroll
    for (int kc = 0; kc < K / 32; ++kc) {
        int ko = kc * 32 + quad * 8;
#pragma unroll
        for (int c2 = 0; c2 < 4; ++c2) {
            short8 b = *(const short8*)(Bs + (c2 * 16 + m16) * KP + ko);
            acc[0][c2] = __builtin_amdgcn_mfma_f32_16x16x32_bf16(a0[kc], b, acc[0][c2], 0, 0, 0);
            acc[1][c2] = __builtin_amdgcn_mfma_f32_16x16x32_bf16(a1[kc], b, acc[1][c2], 0, 0, 0);
        }
    }

    float bb[4];
#pragma unroll
    for (int c2 = 0; c2 < 4; ++c2) bb[c2] = bias[base_c + c2 * 16 + m16];
#pragma unroll
    for (int rt = 0; rt < 2; ++rt)
#pragma unroll
        for (int c2 = 0; c2 < 4; ++c2)
#pragma unroll
            for (int r = 0; r < 4; ++r) acc[rt][c2][r] += bb[c2];

    __syncthreads();   // Bs free -> reuse for epilogue tile

    if (ct < 12) {
        uchar_t* ep = smem;    // fp8 tile [128][stride 80]
#pragma unroll
        for (int c2 = 0; c2 < 4; ++c2) {
            int col_l = c2 * 16 + m16;
#pragma unroll
            for (int rt = 0; rt < 2; ++rt)
#pragma unroll
                for (int r = 0; r < 4; ++r)
                    ep[(wave * 32 + rt * 16 + quad * 4 + r) * 80 + col_l] =
                        fp8e4m3(acc[rt][c2][r]);
        }
        __syncthreads();
        uchar_t* dstbase;
        size_t rstride;
        int off;
        if (ct < 4)      { dstbase = qb8; rstride = 256; off = base_c; }
        else if (ct < 8) { dstbase = kvb; rstride = 512; off = base_c - 256; }
        else             { dstbase = kvb; rstride = 512; off = 256 + (base_c - 512); }
#pragma unroll
        for (int i = 0; i < 2; ++i) {
            int ii = t + i * 256;
            int row = ii >> 2, ch = ii & 3;
            int gr = base_r + row;
            if (gr < N)
                *(uint4*)(dstbase + (size_t)gr * rstride + off + ch * 16) =
                    *(const uint4*)(ep + row * 80 + ch * 16);
        }
    } else {
        ushort_t* ep = (ushort_t*)smem;   // bf16 tile [128][stride 68]
#pragma unroll
        for (int c2 = 0; c2 < 4; ++c2) {
            int col_l = c2 * 16 + m16;
#pragma unroll
            for (int rt = 0; rt < 2; ++rt)
#pragma unroll
                for (int r = 0; r < 4; ++r)
                    ep[(wave * 32 + rt * 16 + quad * 4 + r) * 68 + col_l] =
                        bf16rne(acc[rt][c2][r]);
        }
        __syncthreads();
#pragma unroll
        for (int i = 0; i < 4; ++i) {
            int ii = t + i * 256;
            int row = ii >> 3, ch = ii & 7;
            int gr = base_r + row;
            if (gr < N)
                *(uint4*)(skipb + (size_t)gr * 64 + ch * 8) =
                    *(const uint4*)(ep + row * 68 + ch * 8);
        }
    }
}

// ---------------------------------------------------------------------------
// attn v7: packed-fp32 math; q pre-scaled by 1/8; head-mean 0.25 folded in 1/z.
// ---------------------------------------------------------------------------
__device__ __forceinline__ void edge_step3(uint2 k8, uint2 v8, const floatx2* qp,
                                           float& z, floatx2* acp) {
    floatx2 dp = qp[0] * __builtin_amdgcn_cvt_pk_f32_fp8(k8.x, false);
    dp += qp[1] * __builtin_amdgcn_cvt_pk_f32_fp8(k8.x, true);
    dp += qp[2] * __builtin_amdgcn_cvt_pk_f32_fp8(k8.y, false);
    dp += qp[3] * __builtin_amdgcn_cvt_pk_f32_fp8(k8.y, true);
    float d = dp[0] + dp[1];
    d += __shfl_xor(d, 1);
    d += __shfl_xor(d, 2);
    d += __shfl_xor(d, 4);
    float p = __expf(d);
    z += p;
    floatx2 pp = {p, p};
    acp[0] += pp * __builtin_amdgcn_cvt_pk_f32_fp8(v8.x, false);
    acp[1] += pp * __builtin_amdgcn_cvt_pk_f32_fp8(v8.x, true);
    acp[2] += pp * __builtin_amdgcn_cvt_pk_f32_fp8(v8.y, false);
    acp[3] += pp * __builtin_amdgcn_cvt_pk_f32_fp8(v8.y, true);
}

template <bool OUT_BF16>
__global__ __launch_bounds__(256) void attn_agg7(const uchar_t* __restrict__ qb8,
                                                 const uchar_t* __restrict__ kvb,
                                                 const ushort_t* __restrict__ skipb,
                                                 const int* __restrict__ rowptr,
                                                 const int* __restrict__ col,
                                                 void* __restrict__ hout) {
    int node = blockIdx.x * 4 + threadIdx.y;
    if (node >= N_NODES) return;
    int lane = threadIdx.x;
    int half = lane >> 5, sl = lane & 31;
    uint2 qd = *(const uint2*)(qb8 + (size_t)node * 256 + sl * 8);
    const floatx2 s8 = {0.125f, 0.125f};
    floatx2 qp[4];
    qp[0] = s8 * __builtin_amdgcn_cvt_pk_f32_fp8(qd.x, false);
    qp[1] = s8 * __builtin_amdgcn_cvt_pk_f32_fp8(qd.x, true);
    qp[2] = s8 * __builtin_amdgcn_cvt_pk_f32_fp8(qd.y, false);
    qp[3] = s8 * __builtin_amdgcn_cvt_pk_f32_fp8(qd.y, true);
    floatx2 acp[4];
    acp[0] = (floatx2){0.f, 0.f}; acp[1] = (floatx2){0.f, 0.f};
    acp[2] = (floatx2){0.f, 0.f}; acp[3] = (floatx2){0.f, 0.f};
    float z = 0.f;
    int beg = rowptr[node], end = rowptr[node + 1];
    int e = beg + half;
    const size_t loff = (size_t)sl * 8;
    for (; e + 6 < end; e += 8) {
        const uchar_t* p0 = kvb + (size_t)col[e]     * 512 + loff;
        const uchar_t* p1 = kvb + (size_t)col[e + 2] * 512 + loff;
        const uchar_t* p2 = kvb + (size_t)col[e + 4] * 512 + loff;
        const uchar_t* p3 = kvb + (size_t)col[e + 6] * 512 + loff;
        uint2 k0 = *(const uint2*)p0, v0 = *(const uint2*)(p0 + 256);
        uint2 k1 = *(const uint2*)p1, v1 = *(const uint2*)(p1 + 256);
        uint2 k2 = *(const uint2*)p2, v2 = *(const uint2*)(p2 + 256);
        uint2 k3 = *(const uint2*)p3, v3 = *(const uint2*)(p3 + 256);
        edge_step3(k0, v0, qp, z, acp);
        edge_step3(k1, v1, qp, z, acp);
        edge_step3(k2, v2, qp, z, acp);
        edge_step3(k3, v3, qp, z, acp);
    }
    for (; e < end; e += 2) {
        const uchar_t* p0 = kvb + (size_t)col[e] * 512 + loff;
        uint2 k0 = *(const uint2*)p0, v0 = *(const uint2*)(p0 + 256);
        edge_step3(k0, v0, qp, z, acp);
    }
    z += __shfl_xor(z, 32);
    float ac[8] = {acp[0][0], acp[0][1], acp[1][0], acp[1][1],
                   acp[2][0], acp[2][1], acp[3][0], acp[3][1]};
#pragma unroll
    for (int i = 0; i < 8; ++i) ac[i] += __shfl_xor(ac[i], 32);
    float inv = (z > 0.f) ? (0.25f / z) : 0.f;
#pragma unroll
    for (int i = 0; i < 8; ++i) ac[i] *= inv;
#pragma unroll
    for (int i = 0; i < 8; ++i) {
        ac[i] += __shfl_xor(ac[i], 8);
        ac[i] += __shfl_xor(ac[i], 16);
    }
    if (lane < 8) {
        uint4 su = *(const uint4*)(skipb + (size_t)node * 64 + lane * 8);
        float4 s0 = bf4_unpack(su.x, su.y);
        float4 s1 = bf4_unpack(su.z, su.w);
        float o0 = fmaxf(ac[0] + s0.x, 0.f);
        float o1 = fmaxf(ac[1] + s0.y, 0.f);
        float o2 = fmaxf(ac[2] + s0.z, 0.f);
        float o3 = fmaxf(ac[3] + s0.w, 0.f);
        float o4 = fmaxf(ac[4] + s1.x, 0.f);
        float o5 = fmaxf(ac[5] + s1.y, 0.f);
        float o6 = fmaxf(ac[6] + s1.z, 0.f);
        float o7 = fmaxf(ac[7] + s1.w, 0.f);
        if (OUT_BF16) {
            uint4 u;
            u.x = (uint_t)bf16rne(o0) | ((uint_t)bf16rne(o1) << 16);
            u.y = (uint_t)bf16rne(o2) | ((uint_t)bf16rne(o3) << 16);
            u.z = (uint_t)bf16rne(o4) | ((uint_t)bf16rne(o5) << 16);
            u.w = (uint_t)bf16rne(o6) | ((uint_t)bf16rne(o7) << 16);
            *(uint4*)((ushort_t*)hout + (size_t)node * HIDDEN + lane * 8) = u;
        } else {
            float* op = (float*)hout + (size_t)node * HIDDEN + lane * 8;
            *(float4*)(op)     = make_float4(o0, o1, o2, o3);
            *(float4*)(op + 4) = make_float4(o4, o5, o6, o7);
        }
    }
}

// ---------------------------------------------------------------------------
// pool phase A: 512 blocks = (graph, slice of 8). part[(g*8+s)*64 + d].
// ---------------------------------------------------------------------------
__global__ __launch_bounds__(256) void pool_partial(const float* __restrict__ h,
                                                    const int* __restrict__ batch,
                                                    float* __restrict__ part) {
    int g = blockIdx.x >> 3;
    int s = blockIdx.x & 7;
    int start, end;
    graph_range(batch, g, start, end);
    int len = end - start;
    int s0 = start + (len * s) / 8;
    int s1 = start + (len * (s + 1)) / 8;
    int t = threadIdx.x;
    int d = t & 63, chunk = t >> 6;
    float acc = 0.f;
    for (int n = s0 + chunk; n < s1; n += 4) acc += h[(size_t)n * HIDDEN + d];
    __shared__ float sh[256];
    sh[t] = acc;
    __syncthreads();
    if (t < 64)
        part[(size_t)blockIdx.x * 64 + t] = sh[t] + sh[64 + t] + sh[128 + t] + sh[192 + t];
}

// ---------------------------------------------------------------------------
// pool phase B + MLP head: 64 blocks x 256 threads; each GEMV layer split
// k-wise over 4 thread-groups (t>>6) with LDS reduction.
// ---------------------------------------------------------------------------
__global__ __launch_bounds__(256) void head_mlp(const float* __restrict__ part,
                                                const int* __restrict__ batch,
                                                const float* __restrict__ gf,
                                                const float* __restrict__ gW1, const float* __restrict__ gb1,
                                                const float* __restrict__ gW2, const float* __restrict__ gb2,
                                                const float* __restrict__ hW1, const float* __restrict__ hb1,
                                                const float* __restrict__ hW2, const float* __restrict__ hb2,
                                                float* __restrict__ out) {
    int g = blockIdx.x;
    int t = threadIdx.x;
    int d = t & 63, kk = t >> 6;
    int start, end;
    graph_range(batch, g, start, end);
    float cnt = fmaxf((float)(end - start), 1.0f);
    __shared__ float gfs[GLOBAL_DIM];
    __shared__ float fused[2 * HIDDEN];
    __shared__ float g1[HIDDEN];
    __shared__ float h1s[HIDDEN];
    __shared__ float red[256];
    gfs[t] = gf[(size_t)g * GLOBAL_DIM + t];
    if (t < 64) {
        float s = 0.f;
#pragma unroll
        for (int i = 0; i < 8; ++i) s += part[((size_t)g * 8 + i) * 64 + t];
        fused[t] = s / cnt;
    }
    __syncthreads();
    // g1 = relu(gfs @ gW1 + gb1): 256 k -> 64 per group
    {
        float a = 0.f;
        int k0 = kk * 64;
#pragma unroll 4
        for (int k = k0; k < k0 + 64; ++k) a = fmaf(gfs[k], gW1[k * HIDDEN + d], a);
        red[t] = a;
        __syncthreads();
        if (t < 64) g1[t] = fmaxf(red[t] + red[64 + t] + red[128 + t] + red[192 + t] + gb1[t], 0.f);
        __syncthreads();
    }
    // g2 = relu(g1 @ gW2 + gb2): 64 k -> 16 per group
    {
        float a = 0.f;
        int k0 = kk * 16;
#pragma unroll 4
        for (int k = k0; k < k0 + 16; ++k) a = fmaf(g1[k], gW2[k * HIDDEN + d], a);
        red[t] = a;
        __syncthreads();
        if (t < 64) fused[HIDDEN + t] =
            fmaxf(red[t] + red[64 + t] + red[128 + t] + red[192 + t] + gb2[t], 0.f);
        __syncthreads();
    }
    // h1 = relu(fused @ hW1 + hb1): 128 k -> 32 per group
    {
        float a = 0.f;
        int k0 = kk * 32;
#pragma unroll 4
        for (int k = k0; k < k0 + 32; ++k) a = fmaf(fused[k], hW1[k * HIDDEN + d], a);
        red[t] = a;
        __syncthreads();
        if (t < 64) h1s[t] = fmaxf(red[t] + red[64 + t] + red[128 + t] + red[192 + t] + hb1[t], 0.f);
        __syncthreads();
    }
    // out = h1s @ hW2 + hb2: 10 outputs
    if (t < N_CLASSES) {
        float o = hb2[t];
#pragma unroll 4
        for (int k = 0; k < HIDDEN; ++k) o = fmaf(h1s[k], hW2[k * N_CLASSES + t], o);
        out[(size_t)g * N_CLASSES + t] = o;
    }
}

// ---------------------------------------------------------------------------
extern "C" void kernel_launch(void* const* d_in, const int* in_sizes, int n_in,
                              void* d_out, int out_size, void* d_ws, size_t ws_size,
                              hipStream_t stream) {
    const float* x        = (const float*)d_in[0];
    const int*   eidx     = (const int*)d_in[1];
    const int*   batch    = (const int*)d_in[2];
    const float* gfeats   = (const float*)d_in[3];
    const float* c1_Wq = (const float*)d_in[4];  const float* c1_bq = (const float*)d_in[5];
    const float* c1_Wk = (const float*)d_in[6];  const float* c1_bk = (const float*)d_in[7];
    const float* c1_Wv = (const float*)d_in[8];  const float* c1_bv = (const float*)d_in[9];
    const float* c1_Ws = (const float*)d_in[10]; const float* c1_bs = (const float*)d_in[11];
    const float* c2_Wq = (const float*)d_in[12]; const float* c2_bq = (const float*)d_in[13];
    const float* c2_Wk = (const float*)d_in[14]; const float* c2_bk = (const float*)d_in[15];
    const float* c2_Wv = (const float*)d_in[16]; const float* c2_bv = (const float*)d_in[17];
    const float* c2_Ws = (const float*)d_in[18]; const float* c2_bs = (const float*)d_in[19];
    const float* g_W1 = (const float*)d_in[20]; const float* g_b1 = (const float*)d_in[21];
    const float* g_W2 = (const float*)d_in[22]; const float* g_b2 = (const float*)d_in[23];
    const float* h_W1 = (const float*)d_in[24]; const float* h_b1 = (const float*)d_in[25];
    const float* h_W2 = (const float*)d_in[26]; const float* h_b2 = (const float*)d_in[27];
    float* out = (float*)d_out;

    const int* srcp = eidx;
    const int* dstp = eidx + N_EDGES;

    // ---- workspace layout ----
    char* base = (char*)d_ws;
    uchar_t*  kvb  = (uchar_t*)base;  base += (size_t)N_NODES * 512;
    uchar_t*  qb8  = (uchar_t*)base;  base += (size_t)N_NODES * 256;
    ushort_t* skipb = (ushort_t*)base; base += (size_t)N_NODES * HIDDEN * 2;
    ushort_t* h1b  = (ushort_t*)base; base += (size_t)N_NODES * HIDDEN * 2;
    float*    h2   = (float*)base;    base += (size_t)N_NODES * HIDDEN * 4;
    ushort_t* Wt1  = (ushort_t*)base; base += (size_t)IN_CH * QKV_COLS * 2;
    ushort_t* Wt2  = (ushort_t*)base; base += (size_t)HIDDEN * QKV_COLS * 2;
    float*    bcat1 = (float*)base;   base += QKV_COLS * 4;
    float*    bcat2 = (float*)base;   base += QKV_COLS * 4;
    float*    part = (float*)base;    base += (size_t)N_GRAPHS * 8 * 64 * 4;
    int* ib = (int*)base;
    size_t oi = 0;
    int* deg    = ib + oi; oi += N_NODES;
    int* incl   = ib + oi; oi += N_NODES;
    int* bsums  = ib + oi; oi += 64;
    int* rowptr = ib + oi; oi += N_NODES + 4;
    int* cur    = ib + oi; oi += N_NODES;
    int* colb   = ib + oi; oi += N_EDGES;

    const int NB1 = (N_NODES + 1023) / 1024;   // 49
    const int NBS = (N_NODES + 255) / 256;     // 196
    const int EB  = (N_EDGES + 255) / 256;     // 3125

    const int RB = (N_NODES + 127) / 128;      // 391
    const int GG = 8 * 13 * ((RB + 7) / 8);    // 5096
    dim3 attn_block(64, 4);
    int attn_grid = (N_NODES + 3) / 4;         // 12500

    // ---- CSR + weight prep ----
    hipMemsetAsync(deg, 0, N_NODES * sizeof(int), stream);
    prep2<<<PREP_BLOCKS, 256, 0, stream>>>(
        c1_Wq, c1_Wk, c1_Wv, c1_Ws, c1_bq, c1_bk, c1_bv, c1_bs,
        c2_Wq, c2_Wk, c2_Wv, c2_Ws, c2_bq, c2_bk, c2_bv, c2_bs,
        Wt1, Wt2, bcat1, bcat2, dstp, deg);
    scan1<<<NB1, 1024, 0, stream>>>(deg, incl, bsums, N_NODES);
    scan3f<<<NBS, 256, 0, stream>>>(deg, incl, bsums, rowptr, cur, N_NODES);
    fill_col<<<EB, 256, 0, stream>>>(srcp, dstp, cur, colb);

    // ---- conv1 (A = x fp32, cast in-register; B staged in LDS) ----
    gemm_v9<IN_CH, true><<<GG, 256, 0, stream>>>(x, Wt1, bcat1, qb8, kvb, skipb, N_NODES, RB);
    attn_agg7<true><<<attn_grid, attn_block, 0, stream>>>(qb8, kvb, skipb, rowptr, colb, h1b);

    // ---- conv2 (A = h1b bf16) ----
    gemm_v9<HIDDEN, false><<<GG, 256, 0, stream>>>(h1b, Wt2, bcat2, qb8, kvb, skipb, N_NODES, RB);
    attn_agg7<false><<<attn_grid, attn_block, 0, stream>>>(qb8, kvb, skipb, rowptr, colb, h2);

    // ---- pool (parallel partial) + head ----
    pool_partial<<<N_GRAPHS * 8, 256, 0, stream>>>(h2, batch, part);
    head_mlp<<<N_GRAPHS, 256, 0, stream>>>(part, batch, gfeats,
                                           g_W1, g_b1, g_W2, g_b2,
                                           h_W1, h_b1, h_W2, h_b2, out);
}

// Round 13
// 419.102 us; speedup vs baseline: 1.1843x; 1.0010x over previous
//
#include <hip/hip_runtime.h>
#include <hip/hip_bf16.h>
#include <math.h>

#define N_NODES   50000
#define N_EDGES   800000
#define N_GRAPHS  64
#define IN_CH     128
#define GLOBAL_DIM 256
#define HIDDEN    64
#define HEADS     4
#define N_CLASSES 10
#define QKV_COLS  832   // 256 q | 256 k | 256 v | 64 skip

typedef unsigned short ushort_t;
typedef unsigned int uint_t;
typedef unsigned char uchar_t;
typedef __attribute__((ext_vector_type(8))) short short8;
typedef __attribute__((ext_vector_type(4))) float floatx4;
typedef __attribute__((ext_vector_type(2))) float floatx2;

// ---------------------------------------------------------------------------
// helpers
// ---------------------------------------------------------------------------
__device__ __forceinline__ ushort_t bf16rne(float f) {
    uint_t b = __float_as_uint(f);
    b += 0x7fffu + ((b >> 16) & 1u);
    return (ushort_t)(b >> 16);
}
__device__ __forceinline__ float4 bf4_unpack(uint_t lo, uint_t hi) {
    float4 f;
    f.x = __uint_as_float(lo << 16);
    f.y = __uint_as_float(lo & 0xffff0000u);
    f.z = __uint_as_float(hi << 16);
    f.w = __uint_as_float(hi & 0xffff0000u);
    return f;
}
__device__ __forceinline__ uchar_t fp8e4m3(float f) {
    int v = __builtin_amdgcn_cvt_pk_fp8_f32(f, 0.f, 0, false);
    return (uchar_t)(v & 0xff);
}
__device__ __forceinline__ short8 pack_bf8(float4 a, float4 b) {
    union { short8 s; ushort_t u[8]; } r;
    r.u[0] = bf16rne(a.x); r.u[1] = bf16rne(a.y);
    r.u[2] = bf16rne(a.z); r.u[3] = bf16rne(a.w);
    r.u[4] = bf16rne(b.x); r.u[5] = bf16rne(b.y);
    r.u[6] = bf16rne(b.z); r.u[7] = bf16rne(b.w);
    return r.s;
}
__device__ __forceinline__ void graph_range(const int* __restrict__ batch, int g,
                                            int& start, int& end) {
    int lo = 0, hi = N_NODES;
    while (lo < hi) { int mid = (lo + hi) >> 1; if (batch[mid] < g) lo = mid + 1; else hi = mid; }
    start = lo;
    hi = N_NODES;
    while (lo < hi) { int mid = (lo + hi) >> 1; if (batch[mid] < g + 1) lo = mid + 1; else hi = mid; }
    end = lo;
}

// ---------------------------------------------------------------------------
// PREP: concat both layers' weights  ||  count_deg
// ---------------------------------------------------------------------------
#define PREP_CONC_B  624
#define PREP_CNT_B   1024
#define PREP_BLOCKS  (PREP_CONC_B + PREP_CNT_B)

__global__ __launch_bounds__(256) void prep2(
        const float* __restrict__ W1q, const float* __restrict__ W1k,
        const float* __restrict__ W1v, const float* __restrict__ W1s,
        const float* __restrict__ b1q, const float* __restrict__ b1k,
        const float* __restrict__ b1v, const float* __restrict__ b1s,
        const float* __restrict__ W2q, const float* __restrict__ W2k,
        const float* __restrict__ W2v, const float* __restrict__ W2s,
        const float* __restrict__ b2q, const float* __restrict__ b2k,
        const float* __restrict__ b2v, const float* __restrict__ b2s,
        ushort_t* __restrict__ Wt1, ushort_t* __restrict__ Wt2,
        float* __restrict__ bcat1, float* __restrict__ bcat2,
        const int* __restrict__ dst, int* __restrict__ deg) {
    int b = blockIdx.x, t = threadIdx.x;
    if (b < PREP_CONC_B) {
        int idx = b * 256 + t;
        const int T1 = IN_CH * QKV_COLS;
        const int T2 = HIDDEN * QKV_COLS;
        if (idx < T1) {
            int c = idx / IN_CH, k = idx % IN_CH;
            float v;
            if (c < 256)      v = W1q[k * 256 + c];
            else if (c < 512) v = W1k[k * 256 + (c - 256)];
            else if (c < 768) v = W1v[k * 256 + (c - 512)];
            else              v = W1s[k * 64  + (c - 768)];
            Wt1[idx] = bf16rne(v);
        } else if (idx < T1 + T2) {
            int i2 = idx - T1;
            int c = i2 / HIDDEN, k = i2 % HIDDEN;
            float v;
            if (c < 256)      v = W2q[k * 256 + c];
            else if (c < 512) v = W2k[k * 256 + (c - 256)];
            else if (c < 768) v = W2v[k * 256 + (c - 512)];
            else              v = W2s[k * 64  + (c - 768)];
            Wt2[i2] = bf16rne(v);
        }
        if (idx < QKV_COLS) {
            float bb, b2;
            if (idx < 256)      { bb = b1q[idx];       b2 = b2q[idx]; }
            else if (idx < 512) { bb = b1k[idx - 256]; b2 = b2k[idx - 256]; }
            else if (idx < 768) { bb = b1v[idx - 512]; b2 = b2v[idx - 512]; }
            else                { bb = b1s[idx - 768]; b2 = b2s[idx - 768]; }
            bcat1[idx] = bb;
            bcat2[idx] = b2;
        }
    } else {
        int idx = (b - PREP_CONC_B) * 256 + t;
        for (int e = idx; e < N_EDGES; e += PREP_CNT_B * 256)
            atomicAdd(&deg[dst[e]], 1);
    }
}

// ---------------------------------------------------------------------------
// scans
// ---------------------------------------------------------------------------
__global__ void scan1(const int* __restrict__ deg, int* __restrict__ incl,
                      int* __restrict__ bsums, int n) {
    __shared__ int sh[1024];
    int t = threadIdx.x;
    int gid = blockIdx.x * 1024 + t;
    int v = (gid < n) ? deg[gid] : 0;
    sh[t] = v;
    __syncthreads();
    for (int off = 1; off < 1024; off <<= 1) {
        int tmp = (t >= off) ? sh[t - off] : 0;
        __syncthreads();
        sh[t] += tmp;
        __syncthreads();
    }
    if (gid < n) incl[gid] = sh[t];
    if (t == 1023) bsums[blockIdx.x] = sh[1023];
}

__global__ void scan3f(const int* __restrict__ deg, const int* __restrict__ incl,
                       const int* __restrict__ bsums, int* __restrict__ rowptr,
                       int* __restrict__ cur, int n) {
    __shared__ int sb;
    int t = threadIdx.x;
    int b = (int)(blockIdx.x >> 2);
    if (t < 64) {
        int v = (t < b) ? bsums[t] : 0;
#pragma unroll
        for (int off = 1; off < 64; off <<= 1) v += __shfl_xor(v, off);
        if (t == 0) sb = v;
    }
    __syncthreads();
    int gid = blockIdx.x * 256 + t;
    if (gid < n) {
        int in = incl[gid] + sb;
        int ex = in - deg[gid];
        rowptr[gid] = ex;
        cur[gid] = ex;
        if (gid == n - 1) rowptr[n] = in;
    }
}

// ---------------------------------------------------------------------------
// GEMM v9 body (round-7 winner): B staged in LDS, A fragments direct from
// global, A_FP32 for conv1. XCD-swizzled 1D index; LDS-tiled epilogue.
// Outputs: ct 0-3 q fp8 | ct 4-7 k fp8 | ct 8-11 v fp8 | ct 12 skip bf16.
// ---------------------------------------------------------------------------
template <int K, bool A_FP32>
__device__ __forceinline__ void gemm_body9(int idx0, int t,
                                           const void* __restrict__ Av,
                                           const ushort_t* __restrict__ Wt,
                                           const float* __restrict__ bias,
                                           uchar_t* __restrict__ qb8,
                                           uchar_t* __restrict__ kvb,
                                           ushort_t* __restrict__ skipb,
                                           int N, int RB, uchar_t* smem) {
    constexpr int KP = K + 8;
    constexpr int C8 = K / 8;
    ushort_t* Bs = (ushort_t*)smem;

    const int xcd = idx0 & 7;
    const int j = idx0 >> 3;
    const int ct = j % 13;
    const int strip = (j / 13) * 8 + xcd;
    if (strip >= RB) return;
    const int base_r = strip * 128;
    const int base_c = ct * 64;

#pragma unroll
    for (int i = 0; i < (64 * C8) / 256; ++i) {
        int ii = t + i * 256;
        int n = ii / C8, c = ii % C8;
        *(uint4*)(Bs + n * KP + c * 8) =
            *(const uint4*)(Wt + (size_t)(base_c + n) * K + c * 8);
    }

    const int wave = t >> 6, lane = t & 63;
    const int quad = lane >> 4, m16 = lane & 15;

    int arow0 = base_r + wave * 32 + m16;
    int arow1 = arow0 + 16;
    int cr0 = arow0 < N ? arow0 : N - 1;
    int cr1 = arow1 < N ? arow1 : N - 1;
    short8 a0[K / 32], a1[K / 32];
    if (A_FP32) {
        const float* A = (const float*)Av;
        const float* Ar0 = A + (size_t)cr0 * K + quad * 8;
        const float* Ar1 = A + (size_t)cr1 * K + quad * 8;
#pragma unroll
        for (int kc = 0; kc < K / 32; ++kc) {
            float4 f0 = *(const float4*)(Ar0 + kc * 32);
            float4 f1 = *(const float4*)(Ar0 + kc * 32 + 4);
            a0[kc] = pack_bf8(f0, f1);
            float4 g0 = *(const float4*)(Ar1 + kc * 32);
            float4 g1 = *(const float4*)(Ar1 + kc * 32 + 4);
            a1[kc] = pack_bf8(g0, g1);
        }
    } else {
        const ushort_t* A = (const ushort_t*)Av;
        const ushort_t* Ar0 = A + (size_t)cr0 * K + quad * 8;
        const ushort_t* Ar1 = A + (size_t)cr1 * K + quad * 8;
#pragma unroll
        for (int kc = 0; kc < K / 32; ++kc) {
            a0[kc] = *(const short8*)(Ar0 + kc * 32);
            a1[kc] = *(const short8*)(Ar1 + kc * 32);
        }
    }
    __syncthreads();   // Bs ready

    floatx4 acc[2][4];
#pragma unroll
    for (int rt = 0; rt < 2; ++rt)
#pragma unroll
        for (int c2 = 0; c2 < 4; ++c2) acc[rt][c2] = (floatx4){0.f, 0.f, 0.f, 0.f};
#pragma unroll
    for (int kc = 0; kc < K / 32; ++kc) {
        int ko = kc * 32 + quad * 8;
#pragma unroll
        for (int c2 = 0; c2 < 4; ++c2) {
            short8 b = *(const short8*)(Bs + (c2 * 16 + m16) * KP + ko);
            acc[0][c2] = __builtin_amdgcn_mfma_f32_16x16x32_bf16(a0[kc], b, acc[0][c2], 0, 0, 0);
            acc[1][c2] = __builtin_amdgcn_mfma_f32_16x16x32_bf16(a1[kc], b, acc[1][c2], 0, 0, 0);
        }
    }

    float bb[4];
#pragma unroll
    for (int c2 = 0; c2 < 4; ++c2) bb[c2] = bias[base_c + c2 * 16 + m16];
#pragma unroll
    for (int rt = 0; rt < 2; ++rt)
#pragma unroll
        for (int c2 = 0; c2 < 4; ++c2)
#pragma unroll
            for (int r = 0; r < 4; ++r) acc[rt][c2][r] += bb[c2];

    __syncthreads();   // Bs free -> reuse for epilogue tile

    if (ct < 12) {
        uchar_t* ep = smem;    // fp8 tile [128][stride 80]
#pragma unroll
        for (int c2 = 0; c2 < 4; ++c2) {
            int col_l = c2 * 16 + m16;
#pragma unroll
            for (int rt = 0; rt < 2; ++rt)
#pragma unroll
                for (int r = 0; r < 4; ++r)
                    ep[(wave * 32 + rt * 16 + quad * 4 + r) * 80 + col_l] =
                        fp8e4m3(acc[rt][c2][r]);
        }
        __syncthreads();
        uchar_t* dstbase;
        size_t rstride;
        int off;
        if (ct < 4)      { dstbase = qb8; rstride = 256; off = base_c; }
        else if (ct < 8) { dstbase = kvb; rstride = 512; off = base_c - 256; }
        else             { dstbase = kvb; rstride = 512; off = 256 + (base_c - 512); }
#pragma unroll
        for (int i = 0; i < 2; ++i) {
            int ii = t + i * 256;
            int row = ii >> 2, ch = ii & 3;
            int gr = base_r + row;
            if (gr < N)
                *(uint4*)(dstbase + (size_t)gr * rstride + off + ch * 16) =
                    *(const uint4*)(ep + row * 80 + ch * 16);
        }
    } else {
        ushort_t* ep = (ushort_t*)smem;   // bf16 tile [128][stride 68]
#pragma unroll
        for (int c2 = 0; c2 < 4; ++c2) {
            int col_l = c2 * 16 + m16;
#pragma unroll
            for (int rt = 0; rt < 2; ++rt)
#pragma unroll
                for (int r = 0; r < 4; ++r)
                    ep[(wave * 32 + rt * 16 + quad * 4 + r) * 68 + col_l] =
                        bf16rne(acc[rt][c2][r]);
        }
        __syncthreads();
#pragma unroll
        for (int i = 0; i < 4; ++i) {
            int ii = t + i * 256;
            int row = ii >> 3, ch = ii & 7;
            int gr = base_r + row;
            if (gr < N)
                *(uint4*)(skipb + (size_t)gr * 64 + ch * 8) =
                    *(const uint4*)(ep + row * 68 + ch * 8);
        }
    }
}

// conv1 GEMM with fill_col blocks FIRST ([0,FB2)): the latency-bound atomic
// scatter waves become co-resident with MFMA waves from dispatch slot 0.
#define FB2 782
template <int K, bool A_FP32>
__global__ __launch_bounds__(256) void gemm_fill9(const void* __restrict__ Av,
                                                  const ushort_t* __restrict__ Wt,
                                                  const float* __restrict__ bias,
                                                  uchar_t* __restrict__ qb8,
                                                  uchar_t* __restrict__ kvb,
                                                  ushort_t* __restrict__ skipb,
                                                  int N, int RB,
                                                  const int* __restrict__ src,
                                                  const int* __restrict__ dst,
                                                  int* __restrict__ cur,
                                                  int* __restrict__ col) {
    __shared__ uchar_t smem[17408] __attribute__((aligned(16)));
    int t = threadIdx.x;
    int idx = (int)blockIdx.x;
    if (idx < FB2) {
        int e0 = idx * 1024 + t;
#pragma unroll
        for (int jj = 0; jj < 4; ++jj) {
            int e = e0 + jj * 256;
            if (e < N_EDGES) {
                int d = dst[e];
                int pos = atomicAdd(&cur[d], 1);
                col[pos] = src[e];
            }
        }
        return;
    }
    gemm_body9<K, A_FP32>(idx - FB2, t, Av, Wt, bias, qb8, kvb, skipb, N, RB, smem);
}

template <int K, bool A_FP32>
__global__ __launch_bounds__(256) void gemm_v9(const void* __restrict__ Av,
                                               const ushort_t* __restrict__ Wt,
                                               const float* __restrict__ bias,
                                               uchar_t* __restrict__ qb8,
                                               uchar_t* __restrict__ kvb,
                                               ushort_t* __restrict__ skipb,
                                               int N, int RB) {
    __shared__ uchar_t smem[17408] __attribute__((aligned(16)));
    gemm_body9<K, A_FP32>((int)blockIdx.x, threadIdx.x, Av, Wt, bias,
                          qb8, kvb, skipb, N, RB, smem);
}

// ---------------------------------------------------------------------------
// attn v7: packed-fp32 math; q pre-scaled by 1/8; head-mean 0.25 folded in 1/z.
// ---------------------------------------------------------------------------
__device__ __forceinline__ void edge_step3(uint2 k8, uint2 v8, const floatx2* qp,
                                           float& z, floatx2* acp) {
    floatx2 dp = qp[0] * __builtin_amdgcn_cvt_pk_f32_fp8(k8.x, false);
    dp += qp[1] * __builtin_amdgcn_cvt_pk_f32_fp8(k8.x, true);
    dp += qp[2] * __builtin_amdgcn_cvt_pk_f32_fp8(k8.y, false);
    dp += qp[3] * __builtin_amdgcn_cvt_pk_f32_fp8(k8.y, true);
    float d = dp[0] + dp[1];
    d += __shfl_xor(d, 1);
    d += __shfl_xor(d, 2);
    d += __shfl_xor(d, 4);
    float p = __expf(d);
    z += p;
    floatx2 pp = {p, p};
    acp[0] += pp * __builtin_amdgcn_cvt_pk_f32_fp8(v8.x, false);
    acp[1] += pp * __builtin_amdgcn_cvt_pk_f32_fp8(v8.x, true);
    acp[2] += pp * __builtin_amdgcn_cvt_pk_f32_fp8(v8.y, false);
    acp[3] += pp * __builtin_amdgcn_cvt_pk_f32_fp8(v8.y, true);
}

template <bool OUT_BF16>
__global__ __launch_bounds__(256) void attn_agg7(const uchar_t* __restrict__ qb8,
                                                 const uchar_t* __restrict__ kvb,
                                                 const ushort_t* __restrict__ skipb,
                                                 const int* __restrict__ rowptr,
                                                 const int* __restrict__ col,
                                                 void* __restrict__ hout) {
    int node = blockIdx.x * 4 + threadIdx.y;
    if (node >= N_NODES) return;
    int lane = threadIdx.x;
    int half = lane >> 5, sl = lane & 31;
    uint2 qd = *(const uint2*)(qb8 + (size_t)node * 256 + sl * 8);
    const floatx2 s8 = {0.125f, 0.125f};
    floatx2 qp[4];
    qp[0] = s8 * __builtin_amdgcn_cvt_pk_f32_fp8(qd.x, false);
    qp[1] = s8 * __builtin_amdgcn_cvt_pk_f32_fp8(qd.x, true);
    qp[2] = s8 * __builtin_amdgcn_cvt_pk_f32_fp8(qd.y, false);
    qp[3] = s8 * __builtin_amdgcn_cvt_pk_f32_fp8(qd.y, true);
    floatx2 acp[4];
    acp[0] = (floatx2){0.f, 0.f}; acp[1] = (floatx2){0.f, 0.f};
    acp[2] = (floatx2){0.f, 0.f}; acp[3] = (floatx2){0.f, 0.f};
    float z = 0.f;
    int beg = rowptr[node], end = rowptr[node + 1];
    int e = beg + half;
    const size_t loff = (size_t)sl * 8;
    for (; e + 6 < end; e += 8) {
        const uchar_t* p0 = kvb + (size_t)col[e]     * 512 + loff;
        const uchar_t* p1 = kvb + (size_t)col[e + 2] * 512 + loff;
        const uchar_t* p2 = kvb + (size_t)col[e + 4] * 512 + loff;
        const uchar_t* p3 = kvb + (size_t)col[e + 6] * 512 + loff;
        uint2 k0 = *(const uint2*)p0, v0 = *(const uint2*)(p0 + 256);
        uint2 k1 = *(const uint2*)p1, v1 = *(const uint2*)(p1 + 256);
        uint2 k2 = *(const uint2*)p2, v2 = *(const uint2*)(p2 + 256);
        uint2 k3 = *(const uint2*)p3, v3 = *(const uint2*)(p3 + 256);
        edge_step3(k0, v0, qp, z, acp);
        edge_step3(k1, v1, qp, z, acp);
        edge_step3(k2, v2, qp, z, acp);
        edge_step3(k3, v3, qp, z, acp);
    }
    for (; e < end; e += 2) {
        const uchar_t* p0 = kvb + (size_t)col[e] * 512 + loff;
        uint2 k0 = *(const uint2*)p0, v0 = *(const uint2*)(p0 + 256);
        edge_step3(k0, v0, qp, z, acp);
    }
    z += __shfl_xor(z, 32);
    float ac[8] = {acp[0][0], acp[0][1], acp[1][0], acp[1][1],
                   acp[2][0], acp[2][1], acp[3][0], acp[3][1]};
#pragma unroll
    for (int i = 0; i < 8; ++i) ac[i] += __shfl_xor(ac[i], 32);
    float inv = (z > 0.f) ? (0.25f / z) : 0.f;
#pragma unroll
    for (int i = 0; i < 8; ++i) ac[i] *= inv;
#pragma unroll
    for (int i = 0; i < 8; ++i) {
        ac[i] += __shfl_xor(ac[i], 8);
        ac[i] += __shfl_xor(ac[i], 16);
    }
    if (lane < 8) {
        uint4 su = *(const uint4*)(skipb + (size_t)node * 64 + lane * 8);
        float4 s0 = bf4_unpack(su.x, su.y);
        float4 s1 = bf4_unpack(su.z, su.w);
        float o0 = fmaxf(ac[0] + s0.x, 0.f);
        float o1 = fmaxf(ac[1] + s0.y, 0.f);
        float o2 = fmaxf(ac[2] + s0.z, 0.f);
        float o3 = fmaxf(ac[3] + s0.w, 0.f);
        float o4 = fmaxf(ac[4] + s1.x, 0.f);
        float o5 = fmaxf(ac[5] + s1.y, 0.f);
        float o6 = fmaxf(ac[6] + s1.z, 0.f);
        float o7 = fmaxf(ac[7] + s1.w, 0.f);
        if (OUT_BF16) {
            uint4 u;
            u.x = (uint_t)bf16rne(o0) | ((uint_t)bf16rne(o1) << 16);
            u.y = (uint_t)bf16rne(o2) | ((uint_t)bf16rne(o3) << 16);
            u.z = (uint_t)bf16rne(o4) | ((uint_t)bf16rne(o5) << 16);
            u.w = (uint_t)bf16rne(o6) | ((uint_t)bf16rne(o7) << 16);
            *(uint4*)((ushort_t*)hout + (size_t)node * HIDDEN + lane * 8) = u;
        } else {
            float* op = (float*)hout + (size_t)node * HIDDEN + lane * 8;
            *(float4*)(op)     = make_float4(o0, o1, o2, o3);
            *(float4*)(op + 4) = make_float4(o4, o5, o6, o7);
        }
    }
}

// ---------------------------------------------------------------------------
// pool phase A: 512 blocks = (graph, slice of 8). part[(g*8+s)*64 + d].
// ---------------------------------------------------------------------------
__global__ __launch_bounds__(256) void pool_partial(const float* __restrict__ h,
                                                    const int* __restrict__ batch,
                                                    float* __restrict__ part) {
    int g = blockIdx.x >> 3;
    int s = blockIdx.x & 7;
    int start, end;
    graph_range(batch, g, start, end);
    int len = end - start;
    int s0 = start + (len * s) / 8;
    int s1 = start + (len * (s + 1)) / 8;
    int t = threadIdx.x;
    int d = t & 63, chunk = t >> 6;
    float acc = 0.f;
    for (int n = s0 + chunk; n < s1; n += 4) acc += h[(size_t)n * HIDDEN + d];
    __shared__ float sh[256];
    sh[t] = acc;
    __syncthreads();
    if (t < 64)
        part[(size_t)blockIdx.x * 64 + t] = sh[t] + sh[64 + t] + sh[128 + t] + sh[192 + t];
}

// ---------------------------------------------------------------------------
// pool phase B + MLP head: 64 blocks x 256 threads, k-split GEMV layers.
// ---------------------------------------------------------------------------
__global__ __launch_bounds__(256) void head_mlp(const float* __restrict__ part,
                                                const int* __restrict__ batch,
                                                const float* __restrict__ gf,
                                                const float* __restrict__ gW1, const float* __restrict__ gb1,
                                                const float* __restrict__ gW2, const float* __restrict__ gb2,
                                                const float* __restrict__ hW1, const float* __restrict__ hb1,
                                                const float* __restrict__ hW2, const float* __restrict__ hb2,
                                                float* __restrict__ out) {
    int g = blockIdx.x;
    int t = threadIdx.x;
    int d = t & 63, kk = t >> 6;
    int start, end;
    graph_range(batch, g, start, end);
    float cnt = fmaxf((float)(end - start), 1.0f);
    __shared__ float gfs[GLOBAL_DIM];
    __shared__ float fused[2 * HIDDEN];
    __shared__ float g1[HIDDEN];
    __shared__ float h1s[HIDDEN];
    __shared__ float red[256];
    gfs[t] = gf[(size_t)g * GLOBAL_DIM + t];
    if (t < 64) {
        float s = 0.f;
#pragma unroll
        for (int i = 0; i < 8; ++i) s += part[((size_t)g * 8 + i) * 64 + t];
        fused[t] = s / cnt;
    }
    __syncthreads();
    {
        float a = 0.f;
        int k0 = kk * 64;
#pragma unroll 4
        for (int k = k0; k < k0 + 64; ++k) a = fmaf(gfs[k], gW1[k * HIDDEN + d], a);
        red[t] = a;
        __syncthreads();
        if (t < 64) g1[t] = fmaxf(red[t] + red[64 + t] + red[128 + t] + red[192 + t] + gb1[t], 0.f);
        __syncthreads();
    }
    {
        float a = 0.f;
        int k0 = kk * 16;
#pragma unroll 4
        for (int k = k0; k < k0 + 16; ++k) a = fmaf(g1[k], gW2[k * HIDDEN + d], a);
        red[t] = a;
        __syncthreads();
        if (t < 64) fused[HIDDEN + t] =
            fmaxf(red[t] + red[64 + t] + red[128 + t] + red[192 + t] + gb2[t], 0.f);
        __syncthreads();
    }
    {
        float a = 0.f;
        int k0 = kk * 32;
#pragma unroll 4
        for (int k = k0; k < k0 + 32; ++k) a = fmaf(fused[k], hW1[k * HIDDEN + d], a);
        red[t] = a;
        __syncthreads();
        if (t < 64) h1s[t] = fmaxf(red[t] + red[64 + t] + red[128 + t] + red[192 + t] + hb1[t], 0.f);
        __syncthreads();
    }
    if (t < N_CLASSES) {
        float o = hb2[t];
#pragma unroll 4
        for (int k = 0; k < HIDDEN; ++k) o = fmaf(h1s[k], hW2[k * N_CLASSES + t], o);
        out[(size_t)g * N_CLASSES + t] = o;
    }
}

// ---------------------------------------------------------------------------
extern "C" void kernel_launch(void* const* d_in, const int* in_sizes, int n_in,
                              void* d_out, int out_size, void* d_ws, size_t ws_size,
                              hipStream_t stream) {
    const float* x        = (const float*)d_in[0];
    const int*   eidx     = (const int*)d_in[1];
    const int*   batch    = (const int*)d_in[2];
    const float* gfeats   = (const float*)d_in[3];
    const float* c1_Wq = (const float*)d_in[4];  const float* c1_bq = (const float*)d_in[5];
    const float* c1_Wk = (const float*)d_in[6];  const float* c1_bk = (const float*)d_in[7];
    const float* c1_Wv = (const float*)d_in[8];  const float* c1_bv = (const float*)d_in[9];
    const float* c1_Ws = (const float*)d_in[10]; const float* c1_bs = (const float*)d_in[11];
    const float* c2_Wq = (const float*)d_in[12]; const float* c2_bq = (const float*)d_in[13];
    const float* c2_Wk = (const float*)d_in[14]; const float* c2_bk = (const float*)d_in[15];
    const float* c2_Wv = (const float*)d_in[16]; const float* c2_bv = (const float*)d_in[17];
    const float* c2_Ws = (const float*)d_in[18]; const float* c2_bs = (const float*)d_in[19];
    const float* g_W1 = (const float*)d_in[20]; const float* g_b1 = (const float*)d_in[21];
    const float* g_W2 = (const float*)d_in[22]; const float* g_b2 = (const float*)d_in[23];
    const float* h_W1 = (const float*)d_in[24]; const float* h_b1 = (const float*)d_in[25];
    const float* h_W2 = (const float*)d_in[26]; const float* h_b2 = (const float*)d_in[27];
    float* out = (float*)d_out;

    const int* srcp = eidx;
    const int* dstp = eidx + N_EDGES;

    // ---- workspace layout ----
    char* base = (char*)d_ws;
    uchar_t*  kvb  = (uchar_t*)base;  base += (size_t)N_NODES * 512;
    uchar_t*  qb8  = (uchar_t*)base;  base += (size_t)N_NODES * 256;
    ushort_t* skipb = (ushort_t*)base; base += (size_t)N_NODES * HIDDEN * 2;
    ushort_t* h1b  = (ushort_t*)base; base += (size_t)N_NODES * HIDDEN * 2;
    float*    h2   = (float*)base;    base += (size_t)N_NODES * HIDDEN * 4;
    ushort_t* Wt1  = (ushort_t*)base; base += (size_t)IN_CH * QKV_COLS * 2;
    ushort_t* Wt2  = (ushort_t*)base; base += (size_t)HIDDEN * QKV_COLS * 2;
    float*    bcat1 = (float*)base;   base += QKV_COLS * 4;
    float*    bcat2 = (float*)base;   base += QKV_COLS * 4;
    float*    part = (float*)base;    base += (size_t)N_GRAPHS * 8 * 64 * 4;
    int* ib = (int*)base;
    size_t oi = 0;
    int* deg    = ib + oi; oi += N_NODES;
    int* incl   = ib + oi; oi += N_NODES;
    int* bsums  = ib + oi; oi += 64;
    int* rowptr = ib + oi; oi += N_NODES + 4;
    int* cur    = ib + oi; oi += N_NODES;
    int* colb   = ib + oi; oi += N_EDGES;

    const int NB1 = (N_NODES + 1023) / 1024;   // 49
    const int NBS = (N_NODES + 255) / 256;     // 196

    const int RB = (N_NODES + 127) / 128;      // 391
    const int GG = 8 * 13 * ((RB + 7) / 8);    // 5096
    dim3 attn_block(64, 4);
    int attn_grid = (N_NODES + 3) / 4;         // 12500

    // ---- CSR + weight prep ----
    hipMemsetAsync(deg, 0, N_NODES * sizeof(int), stream);
    prep2<<<PREP_BLOCKS, 256, 0, stream>>>(
        c1_Wq, c1_Wk, c1_Wv, c1_Ws, c1_bq, c1_bk, c1_bv, c1_bs,
        c2_Wq, c2_Wk, c2_Wv, c2_Ws, c2_bq, c2_bk, c2_bv, c2_bs,
        Wt1, Wt2, bcat1, bcat2, dstp, deg);
    scan1<<<NB1, 1024, 0, stream>>>(deg, incl, bsums, N_NODES);
    scan3f<<<NBS, 256, 0, stream>>>(deg, incl, bsums, rowptr, cur, N_NODES);

    // ---- conv1 GEMM || fill_col (fill blocks FIRST) ----
    gemm_fill9<IN_CH, true><<<FB2 + GG, 256, 0, stream>>>(
        x, Wt1, bcat1, qb8, kvb, skipb, N_NODES, RB, srcp, dstp, cur, colb);
    attn_agg7<true><<<attn_grid, attn_block, 0, stream>>>(qb8, kvb, skipb, rowptr, colb, h1b);

    // ---- conv2 (A = h1b bf16) ----
    gemm_v9<HIDDEN, false><<<GG, 256, 0, stream>>>(h1b, Wt2, bcat2, qb8, kvb, skipb, N_NODES, RB);
    attn_agg7<false><<<attn_grid, attn_block, 0, stream>>>(qb8, kvb, skipb, rowptr, colb, h2);

    // ---- pool (parallel partial) + head ----
    pool_partial<<<N_GRAPHS * 8, 256, 0, stream>>>(h2, batch, part);
    head_mlp<<<N_GRAPHS, 256, 0, stream>>>(part, batch, gfeats,
                                           g_W1, g_b1, g_W2, g_b2,
                                           h_W1, h_b1, h_W2, h_b2, out);
}